// Round 7
// baseline (555.718 us; speedup 1.0000x reference)
//
#include <hip/hip_runtime.h>
#include <cmath>

// Problem constants
// B=8, C=256, H=W=64, HW=4096, NT=32768 tokens
// heads M=8, head dim D=32, regions NR=64 (8x8 of 8x8), RSQ=64, TOPK=4, KSEL=32

typedef __bf16 bf16x8 __attribute__((ext_vector_type(8)));
typedef __bf16 bf16x4 __attribute__((ext_vector_type(4)));
typedef float f32x4 __attribute__((ext_vector_type(4)));
typedef float f32x2 __attribute__((ext_vector_type(2)));
typedef unsigned short us4 __attribute__((ext_vector_type(4)));

__device__ __forceinline__ void async_copy16(const __bf16* g, __bf16* l) {
  __builtin_amdgcn_global_load_lds(
      (const __attribute__((address_space(1))) void*)g,
      (__attribute__((address_space(3))) void*)l, 16, 0, 0);
}

// ---------------------------------------------------------------------------
// Tiled transpose: per batch, src [R][Cc] -> dst [Cc][R]. 64x64 tiles.
// ---------------------------------------------------------------------------
__global__ __launch_bounds__(256) void transpose_kernel(
    const float* __restrict__ src, float* __restrict__ dst, int R, int Cc) {
  __shared__ float T[64][65];
  int b = blockIdx.z;
  int r0 = blockIdx.y * 64, c0 = blockIdx.x * 64;
  const float* S = src + (size_t)b * R * Cc;
  float* D = dst + (size_t)b * R * Cc;
  int lane = threadIdx.x & 63, wq = threadIdx.x >> 6;
#pragma unroll
  for (int j = 0; j < 16; j++) {
    int rr = wq + j * 4;
    T[rr][lane] = S[(size_t)(r0 + rr) * Cc + c0 + lane];
  }
  __syncthreads();
#pragma unroll
  for (int j = 0; j < 16; j++) {
    int cc = wq + j * 4;
    D[(size_t)(c0 + cc) * R + r0 + lane] = T[lane][cc];
  }
}

// ---------------------------------------------------------------------------
// K1: xa = xt + dwconv3x3(xt,pos), all NHWC.
// ---------------------------------------------------------------------------
__global__ __launch_bounds__(256) void posconv_kernel(
    const float* __restrict__ xt, const float* __restrict__ pw,
    const float* __restrict__ pb, float* __restrict__ xa) {
  __shared__ float Ls[100][64];
  __shared__ float Ws[9][64];
  int blk = blockIdx.x;  // 8*64*4
  int b = blk >> 8, r = (blk >> 2) & 63, cg = blk & 3;
  int h0 = (r >> 3) << 3, w0 = (r & 7) << 3;
  int c0 = cg << 6;
  int tid = threadIdx.x, cl = tid & 63;
  const float* src = xt + ((size_t)b * 4096) * 256;
  for (int i = tid; i < 6400; i += 256) {
    int pos = i >> 6, ccl = i & 63;
    int hh = h0 + (pos / 10) - 1, ww = w0 + (pos % 10) - 1;
    float val = 0.f;
    if (hh >= 0 && hh < 64 && ww >= 0 && ww < 64)
      val = src[(size_t)(hh * 64 + ww) * 256 + c0 + ccl];
    Ls[pos][ccl] = val;
  }
  for (int i = tid; i < 576; i += 256) {
    int tap = i >> 6, ccl = i & 63;
    Ws[tap][ccl] = pw[(c0 + ccl) * 9 + tap];
  }
  __syncthreads();
  float bias = pb[c0 + cl];
  for (int j = 0; j < 16; j++) {
    int p = (tid >> 6) + (j << 2);
    int ph = p >> 3, pww = p & 7;
    float acc = bias;
#pragma unroll
    for (int dh = 0; dh < 3; dh++)
#pragma unroll
      for (int dw = 0; dw < 3; dw++)
        acc += Ls[(ph + dh) * 10 + (pww + dw)][cl] * Ws[dh * 3 + dw][cl];
    float xv = Ls[(ph + 1) * 10 + (pww + 1)][cl];
    xa[((size_t)(b * 4096 + (h0 + ph) * 64 + (w0 + pww))) * 256 + c0 + cl] =
        xv + acc;
  }
}

// ---------------------------------------------------------------------------
// FUSED LN1 + region-mean: block per (b, region), 4 waves x 16 tokens.
// ---------------------------------------------------------------------------
__global__ __launch_bounds__(256) void ln1mean_kernel(
    const float* __restrict__ xa, const float* __restrict__ g,
    const float* __restrict__ bb, __bf16* __restrict__ lnb,
    float* __restrict__ lnm) {
  __shared__ float part[4][256];
  int blk = blockIdx.x;  // 8*64
  int b = blk >> 6, r = blk & 63;
  int h0 = (r >> 3) << 3, w0 = (r & 7) << 3;
  int wave = threadIdx.x >> 6, l = threadIdx.x & 63;
  float ga = g[l], gb2 = g[l + 64], gc = g[l + 128], gd = g[l + 192];
  float ba = bb[l], bb2 = bb[l + 64], bc = bb[l + 128], bd = bb[l + 192];
  float a0 = 0.f, a1 = 0.f, a2 = 0.f, a3 = 0.f;
  for (int t = 0; t < 16; t++) {
    int p = wave * 16 + t;
    int h = h0 + (p >> 3), w = w0 + (p & 7);
    size_t tok = (size_t)(b * 4096 + h * 64 + w) * 256;
    const float* row = xa + tok;
    float v0 = row[l], v1 = row[l + 64], v2 = row[l + 128], v3 = row[l + 192];
    float s = v0 + v1 + v2 + v3;
#pragma unroll
    for (int off = 32; off; off >>= 1) s += __shfl_xor(s, off);
    float mu = s * (1.f / 256.f);
    float d0 = v0 - mu, d1 = v1 - mu, d2 = v2 - mu, d3 = v3 - mu;
    float sq = d0 * d0 + d1 * d1 + d2 * d2 + d3 * d3;
#pragma unroll
    for (int off = 32; off; off >>= 1) sq += __shfl_xor(sq, off);
    float rstd = rsqrtf(sq * (1.f / 256.f) + 1e-6f);
    float n0 = d0 * rstd, n1 = d1 * rstd, n2 = d2 * rstd, n3 = d3 * rstd;
    __bf16* o = lnb + tok;
    o[l]       = (__bf16)(n0 * ga + ba);
    o[l + 64]  = (__bf16)(n1 * gb2 + bb2);
    o[l + 128] = (__bf16)(n2 * gc + bc);
    o[l + 192] = (__bf16)(n3 * gd + bd);
    a0 += n0; a1 += n1; a2 += n2; a3 += n3;
  }
  part[wave][l] = a0; part[wave][l + 64] = a1;
  part[wave][l + 128] = a2; part[wave][l + 192] = a3;
  __syncthreads();
  if (wave == 0) {
    for (int ch = l; ch < 256; ch += 64) {
      float s2 = part[0][ch] + part[1][ch] + part[2][ch] + part[3][ch];
      lnm[(size_t)(b * 64 + r) * 256 + ch] = g[ch] * (s2 * (1.f / 64.f)) + bb[ch];
    }
  }
}

// ---------------------------------------------------------------------------
// Weight prep: bf16-convert qkv_w [768][256], out_w [256][256],
// transpose+convert mlp_w1 [256][768]->[768][256], mlp_w2 [768][256]->[256][768]
// ---------------------------------------------------------------------------
__global__ __launch_bounds__(256) void wprep_kernel(
    const float* __restrict__ qkv_w, const float* __restrict__ out_w,
    const float* __restrict__ w1, const float* __restrict__ w2,
    __bf16* __restrict__ wq, __bf16* __restrict__ wo,
    __bf16* __restrict__ w1t, __bf16* __restrict__ w2t) {
  int i = blockIdx.x * 256 + threadIdx.x;
  if (i < 196608) wq[i] = (__bf16)qkv_w[i];
  if (i < 65536) wo[i] = (__bf16)out_w[i];
  if (i < 196608) {  // w1t[n][k] = w1[k][n], n<768, k<256
    int n = i >> 8, k2 = i & 255;
    w1t[i] = (__bf16)w1[k2 * 768 + n];
  }
  if (i < 196608) {  // w2t[n][k] = w2[k][n], n<256, k<768
    int n = i / 768, k2 = i % 768;
    w2t[i] = (__bf16)w2[k2 * 256 + n];
  }
}

// ---------------------------------------------------------------------------
// MFMA bf16 GEMM: C[row][col] = epi( sum_k A[row][k]*Bw[col][k] + bias[col] )
// EPI: 0 = scatter to q(bf16, pre-scaled 1/16)/k,v(bf16) seq layout;
//      2 = gelu -> bf16; 3 = res+val written NCHW fp32
// ---------------------------------------------------------------------------
template <int EPI>
__global__ __launch_bounds__(256) void mfma_gemm(
    const __bf16* __restrict__ A, const __bf16* __restrict__ Bw,
    const float* __restrict__ bias, const float* __restrict__ res,
    float* __restrict__ out, __bf16* __restrict__ outb,
    __bf16* __restrict__ qd, __bf16* __restrict__ kd, __bf16* __restrict__ vd,
    int N, int K, int row0) {
  __shared__ __bf16 Asl[128 * 32];
  __shared__ __bf16 Bsl[128 * 32];
  int tid = threadIdx.x;
  int lane = tid & 63, wave = tid >> 6;
  int m0 = blockIdx.y * 128, n0 = blockIdx.x * 128;
  int wr = (wave >> 1) * 64, wc = (wave & 1) * 64;

  f32x4 acc[4][4];
  f32x4 z = {0.f, 0.f, 0.f, 0.f};
#pragma unroll
  for (int i = 0; i < 4; i++)
#pragma unroll
    for (int j = 0; j < 4; j++) acc[i][j] = z;

  int srow = (lane >> 2);          // 0..15
  int skoff = (lane & 3) * 8;      // 0,8,16,24
  for (int k0 = 0; k0 < K; k0 += 32) {
#pragma unroll
    for (int j = 0; j < 2; j++) {
      int rbase = wave * 32 + j * 16;
      const __bf16* ga = A + (size_t)(m0 + rbase + srow) * K + k0 + skoff;
      const __bf16* gb = Bw + (size_t)(n0 + rbase + srow) * K + k0 + skoff;
      async_copy16(ga, &Asl[rbase * 32]);
      async_copy16(gb, &Bsl[rbase * 32]);
    }
    __syncthreads();
    bf16x8 af[4], bf[4];
#pragma unroll
    for (int t = 0; t < 4; t++) {
      af[t] = *(const bf16x8*)&Asl[(wr + t * 16 + (lane & 15)) * 32 + (lane >> 4) * 8];
      bf[t] = *(const bf16x8*)&Bsl[(wc + t * 16 + (lane & 15)) * 32 + (lane >> 4) * 8];
    }
#pragma unroll
    for (int ti = 0; ti < 4; ti++)
#pragma unroll
      for (int tj = 0; tj < 4; tj++)
        acc[ti][tj] = __builtin_amdgcn_mfma_f32_16x16x32_bf16(
            af[ti], bf[tj], acc[ti][tj], 0, 0, 0);
    __syncthreads();
  }
  // epilogue: C/D layout col=lane&15, row=(lane>>4)*4+reg
#pragma unroll
  for (int ti = 0; ti < 4; ti++) {
#pragma unroll
    for (int tj = 0; tj < 4; tj++) {
      int colg = n0 + wc + tj * 16 + (lane & 15);
      float bv = bias[colg];
#pragma unroll
      for (int reg = 0; reg < 4; reg++) {
        int rowg = m0 + wr + ti * 16 + (lane >> 4) * 4 + reg;
        float val = acc[ti][tj][reg] + bv;
        if (EPI == 0) {
          int tns = colg >> 8, cc = colg & 255, m = cc >> 5, d = cc & 31;
          int grow = row0 + rowg;
          int b = grow >> 12, hw = grow & 4095, h = hw >> 6, w = hw & 63;
          int r = ((h >> 3) << 3) | (w >> 3), s2 = ((h & 7) << 3) | (w & 7);
          size_t addr = (size_t)(b * 8 + m) * 131072 + r * 2048 + s2 * 32 + d;
          if (tns == 0) qd[addr] = (__bf16)(val * 0.0625f);  // fold scale C^-0.5
          else if (tns == 1) kd[addr] = (__bf16)val;
          else vd[addr] = (__bf16)val;
        } else if (EPI == 2) {
          outb[(size_t)rowg * N + colg] =
              (__bf16)(0.5f * val * (1.f + erff(val * 0.70710678118654752f)));
        } else {
          int grow = row0 + rowg;
          int b = grow >> 12, hw = grow & 4095;
          out[(size_t)(b * 256 + colg) * 4096 + hw] =
              res[(size_t)grow * 256 + colg] + val;
        }
      }
    }
  }
}

// ---------------------------------------------------------------------------
// FUSED out-projection + residual + LN2: 512 thr, 128x256 tile (full C rows),
// grid = 256 row-blocks. Replaces mfma_gemm<1> + ln_kernel.
// ---------------------------------------------------------------------------
__global__ __launch_bounds__(512) void gemm_ln_kernel(
    const __bf16* A, const __bf16* __restrict__ Bw,
    const float* __restrict__ bias, float* __restrict__ xa,
    const float* __restrict__ g2, const float* __restrict__ b2,
    __bf16* lnbo) {
  __shared__ __bf16 Asl[128 * 32];
  __shared__ __bf16 Bsl[256 * 32];
  __shared__ float part1[128][4];
  __shared__ float part2[128][4];
  __shared__ float muv[128];
  __shared__ float rsv[128];
  int tid = threadIdx.x;
  int lane = tid & 63, wave = tid >> 6;
  int m0 = blockIdx.x * 128;
  int wr = (wave >> 2) * 64, wc = (wave & 3) * 64;

  f32x4 acc[4][4];
  f32x4 z = {0.f, 0.f, 0.f, 0.f};
#pragma unroll
  for (int i = 0; i < 4; i++)
#pragma unroll
    for (int j = 0; j < 4; j++) acc[i][j] = z;

  int srow = lane >> 2, skoff = (lane & 3) * 8;
  for (int k0 = 0; k0 < 256; k0 += 32) {
#pragma unroll
    for (int j = 0; j < 3; j++) {
      int seg = wave + 8 * j;
      if (seg < 8) {
        const __bf16* ga = A + (size_t)(m0 + seg * 16 + srow) * 256 + k0 + skoff;
        async_copy16(ga, &Asl[seg * 16 * 32]);
      } else {
        const __bf16* gb =
            Bw + (size_t)((seg - 8) * 16 + srow) * 256 + k0 + skoff;
        async_copy16(gb, &Bsl[(seg - 8) * 16 * 32]);
      }
    }
    __syncthreads();
    bf16x8 af[4], bf[4];
#pragma unroll
    for (int t = 0; t < 4; t++) {
      af[t] = *(const bf16x8*)&Asl[(wr + t * 16 + (lane & 15)) * 32 + (lane >> 4) * 8];
      bf[t] = *(const bf16x8*)&Bsl[(wc + t * 16 + (lane & 15)) * 32 + (lane >> 4) * 8];
    }
#pragma unroll
    for (int ti = 0; ti < 4; ti++)
#pragma unroll
      for (int tj = 0; tj < 4; tj++)
        acc[ti][tj] = __builtin_amdgcn_mfma_f32_16x16x32_bf16(
            af[ti], bf[tj], acc[ti][tj], 0, 0, 0);
    __syncthreads();
  }

  // epilogue phase 1: v = acc + bias + res; write xa; accumulate partials
  float s1[16], s2v[16];
#pragma unroll
  for (int k = 0; k < 16; k++) { s1[k] = 0.f; s2v[k] = 0.f; }
#pragma unroll
  for (int tj = 0; tj < 4; tj++) {
    int colg = wc + tj * 16 + (lane & 15);
    float bv = bias[colg];
#pragma unroll
    for (int ti = 0; ti < 4; ti++) {
#pragma unroll
      for (int reg = 0; reg < 4; reg++) {
        int rowg = m0 + wr + ti * 16 + (lane >> 4) * 4 + reg;
        float v = acc[ti][tj][reg] + bv + xa[(size_t)rowg * 256 + colg];
        xa[(size_t)rowg * 256 + colg] = v;
        acc[ti][tj][reg] = v;  // keep for phase 2
        s1[ti * 4 + reg] += v;
        s2v[ti * 4 + reg] += v * v;
      }
    }
  }
  // reduce over the 16-lane col group (lane&15)
#pragma unroll
  for (int off = 1; off < 16; off <<= 1) {
#pragma unroll
    for (int k = 0; k < 16; k++) {
      s1[k] += __shfl_xor(s1[k], off);
      s2v[k] += __shfl_xor(s2v[k], off);
    }
  }
  if ((lane & 15) == 0) {
    int q = lane >> 4;
#pragma unroll
    for (int k = 0; k < 16; k++) {
      int rowl = wr + (k >> 2) * 16 + q * 4 + (k & 3);
      part1[rowl][wave & 3] = s1[k];
      part2[rowl][wave & 3] = s2v[k];
    }
  }
  __syncthreads();
  if (tid < 128) {
    float S1 = part1[tid][0] + part1[tid][1] + part1[tid][2] + part1[tid][3];
    float S2 = part2[tid][0] + part2[tid][1] + part2[tid][2] + part2[tid][3];
    float mu = S1 * (1.f / 256.f);
    float var = S2 * (1.f / 256.f) - mu * mu;
    muv[tid] = mu;
    rsv[tid] = rsqrtf(var + 1e-6f);
  }
  __syncthreads();
  // phase 2: lnb = (v - mu)*rstd*g + b
#pragma unroll
  for (int tj = 0; tj < 4; tj++) {
    int colg = wc + tj * 16 + (lane & 15);
    float gg = g2[colg], bb = b2[colg];
#pragma unroll
    for (int ti = 0; ti < 4; ti++) {
#pragma unroll
      for (int reg = 0; reg < 4; reg++) {
        int rowl = wr + ti * 16 + (lane >> 4) * 4 + reg;
        int rowg = m0 + rowl;
        lnbo[(size_t)rowg * 256 + colg] =
            (__bf16)((acc[ti][tj][reg] - muv[rowl]) * rsv[rowl] * gg + bb);
      }
    }
  }
}

__global__ __launch_bounds__(256) void qkr_kernel(
    const float* __restrict__ lnm, const float* __restrict__ qkv_w,
    const float* __restrict__ qkv_b, float* __restrict__ qr,
    float* __restrict__ kr) {
  __shared__ float xm[256];
  int br = blockIdx.x, c = threadIdx.x;
  xm[c] = lnm[(size_t)br * 256 + c];
  __syncthreads();
  const float* wqp = qkv_w + (size_t)c * 256;
  const float* wkp = qkv_w + (size_t)(256 + c) * 256;
  float aq = 0.f, ak = 0.f;
  for (int k2 = 0; k2 < 256; k2++) {
    float xv = xm[k2];
    aq += wqp[k2] * xv; ak += wkp[k2] * xv;
  }
  qr[(size_t)br * 256 + c] = aq + qkv_b[c];
  kr[(size_t)br * 256 + c] = ak + qkv_b[256 + c];
}

// ---------------------------------------------------------------------------
// Routing v2: grid (16 row-groups, 8 batches), 4 waves/block.
// ---------------------------------------------------------------------------
__global__ __launch_bounds__(256) void routing_kernel(
    const float* __restrict__ qr, const float* __restrict__ kr,
    int* __restrict__ idxout) {
  __shared__ float Ar[4][64];
  int b = blockIdx.y, rg = blockIdx.x;
  int tid = threadIdx.x;
  int lane = tid & 63, wave = tid >> 6;
  int i = (rg << 2) + wave;
  const float* qrow = qr + (size_t)(b * 64 + i) * 256;
  const float* krow = kr + (size_t)(b * 64 + lane) * 256;
  float acc = 0.f;
  for (int c = 0; c < 256; c++) acc += qrow[c] * krow[c];
  Ar[wave][lane] = acc;
  __syncthreads();
  if (lane == 0) {
    float v0 = -INFINITY, v1 = -INFINITY, v2 = -INFINITY, v3 = -INFINITY;
    int i0 = 0, i1 = 0, i2 = 0, i3 = 0;
    for (int j = 0; j < 64; j++) {
      float s = Ar[wave][j];
      if (s > v0)      { v3=v2;i3=i2; v2=v1;i2=i1; v1=v0;i1=i0; v0=s;i0=j; }
      else if (s > v1) { v3=v2;i3=i2; v2=v1;i2=i1; v1=s;i1=j; }
      else if (s > v2) { v3=v2;i3=i2; v2=s;i2=j; }
      else if (s > v3) { v3=s;i3=j; }
    }
    int* op = idxout + (b * 64 + i) * 4;
    op[0] = i0; op[1] = i1; op[2] = i2; op[3] = i3;
  }
}

// ---------------------------------------------------------------------------
// Attention per (b,m,r) — MFMA, 512 threads / 8 waves, chunks concurrent.
// R7: (a) wsum via append-ones MFMA during PV (kills 6-deep shfl chains +
//     wsum_l LDS round-trip); (b) radix early-exit when count(>=p)==32 for
//     all 8 rows (sticky flags; selection provably identical — ballots
//     compare full 16-bit keys, tie-break handles the equality class).
// LDS: Vt 16K (rotation) + Sb[64][256] 32K = 49.2KB -> 3 blocks/CU, 24 w/CU.
// ---------------------------------------------------------------------------
__global__ __launch_bounds__(512, 6) void attn_kernel(
    const __bf16* __restrict__ qbf, float* __restrict__ aout,
    const __bf16* __restrict__ kbuf, const __bf16* __restrict__ vbuf,
    const int* __restrict__ idx) {
  __shared__ __bf16 Vt[32 * 256];   // rotation layout
  __shared__ __bf16 Sb[64 * 256];   // [row][key ^ ((row&7)<<3)] : S then P
  int blk = blockIdx.x; int r = blk & 63; int m = (blk >> 6) & 7; int b = blk >> 9;
  int tid = threadIdx.x;
  int lane = tid & 63, wave = tid >> 6;   // wave 0..7
  const int* ip = idx + (b * 64 + r) * 4;
  size_t bm = (size_t)(b * 8 + m) * 131072;
  int rgs[4] = {ip[0], ip[1], ip[2], ip[3]};

  // ---- stage V -> Vt (rotation layout), conflict-free b16 writes ----
  {
    int tid2 = tid & 255;
    int rid = tid >> 8;               // 0..1
    int s = tid2 >> 2, g8 = tid2 & 3; // key-in-region, d-chunk
#pragma unroll
    for (int t = 0; t < 2; t++) {
      int rgi = (t << 1) | rid;
      int rlo = (rgi & 1) ? rgs[1] : rgs[0];
      int rhi = (rgi & 1) ? rgs[3] : rgs[2];
      int rgv = (rgi & 2) ? rhi : rlo;
      const uint4* sv = (const uint4*)(vbuf + bm + (size_t)rgv * 2048);
      uint4 vw = sv[tid2];
      int kk = (rgi << 6) | s;
      int ck = kk >> 3, klo = kk & 7;
      union { uint4 u; __bf16 h[8]; } vu; vu.u = vw;
#pragma unroll
      for (int j = 0; j < 8; j++) {
        int d = (g8 << 3) + j;
        int cp = (ck + j + (g8 << 1)) & 31;   // (ck + (d&7) + 2*(d>>3)) & 31
        Vt[(d << 8) + (cp << 3) + klo] = vu.h[j];
      }
    }
  }

  // ---- Q fragments for this wave's chunk (c = wave>>2) ----
  int chnk = wave >> 2;
  const __bf16* qb = qbf + bm + r * 2048;
  bf16x8 qf[2];
#pragma unroll
  for (int rtl = 0; rtl < 2; rtl++) {
    int rt = (chnk << 1) + rtl;
    qf[rtl] = *(const bf16x8*)(qb + ((rt * 16 + (lane & 15)) << 5) + ((lane >> 4) << 3));
  }

  // ---- K fragments direct from global: region rgs[wave&3] ----
  bf16x8 kf[4];
  {
    int rw0 = (wave & 1) ? rgs[1] : rgs[0];
    int rw1 = (wave & 1) ? rgs[3] : rgs[2];
    int rgw = (wave & 2) ? rw1 : rw0;
    const __bf16* kb = kbuf + bm + (size_t)rgw * 2048;
#pragma unroll
    for (int kt4 = 0; kt4 < 4; kt4++)
      kf[kt4] = *(const bf16x8*)(kb + ((kt4 * 16 + (lane & 15)) << 5) + ((lane >> 4) << 3));
  }

  // ---- S^T = K @ Q^T: wave covers (chunk, region) pair ----
#pragma unroll
  for (int kt4 = 0; kt4 < 4; kt4++) {
    int kt = ((wave & 3) << 2) + kt4;   // global key-tile
#pragma unroll
    for (int rtl = 0; rtl < 2; rtl++) {
      f32x4 st = {0.f, 0.f, 0.f, 0.f};
      st = __builtin_amdgcn_mfma_f32_16x16x32_bf16(kf[kt4], qf[rtl], st, 0, 0, 0);
      // D: M(key)=kt*16+4*(lane>>4)+reg ; N(row)=chunk*32+rtl*16+(lane&15)
      int row = (chnk << 5) + (rtl << 4) + (lane & 15);   // 0..63
      int key0 = (kt << 4) + ((lane >> 4) << 2);
      bf16x4 sv4;
#pragma unroll
      for (int j = 0; j < 4; j++) sv4[j] = (__bf16)st[j];
      *(bf16x4*)&Sb[row * 256 + (key0 ^ ((row & 7) << 3))] = sv4;
    }
  }
  __syncthreads();

  // ---- select top-32 per row: rows 8*wave .. 8*wave+7 ----
  {
    int row0 = wave << 3;
    unsigned uk[8][4];
#pragma unroll
    for (int i = 0; i < 8; i++) {
      us4 q4 = *(const us4*)&Sb[(row0 + i) * 256 + ((lane << 2) ^ (i << 3))];
#pragma unroll
      for (int t = 0; t < 4; t++) {
        unsigned bits = q4[t];
        uk[i][t] = (bits ^ ((0u - (bits >> 15)) | 0x8000u)) & 0xFFFFu;
      }
    }
    unsigned p[8];
#pragma unroll
    for (int i = 0; i < 8; i++) p[i] = 0;
    unsigned done = 0;
    for (int bit = 15; bit >= 0; --bit) {
      unsigned msk = 1u << bit;
#pragma unroll
      for (int i = 0; i < 8; i++) {
        unsigned cc = p[i] | msk;
        int n = __popcll(__ballot(uk[i][0] >= cc)) + __popcll(__ballot(uk[i][1] >= cc)) +
                __popcll(__ballot(uk[i][2] >= cc)) + __popcll(__ballot(uk[i][3] >= cc));
        if (n >= 32) p[i] = cc;
        if (n == 32) done |= 1u << i;
      }
      if (done == 255u) break;   // all rows: count(>=p)==32 — set final
    }
#pragma unroll
    for (int i = 0; i < 8; i++) {
      unsigned T = p[i];
      unsigned ub = T << 16;
      unsigned tb = (ub & 0x80000000u) ? (ub ^ 0x80000000u) : ~ub;
      float Tv = __uint_as_float(tb);
      unsigned long long gbb[4], ebb[4];
#pragma unroll
      for (int t = 0; t < 4; t++) {
        gbb[t] = __ballot(uk[i][t] > T);
        ebb[t] = __ballot(uk[i][t] == T);
      }
      int cgt = __popcll(gbb[0]) + __popcll(gbb[1]) + __popcll(gbb[2]) + __popcll(gbb[3]);
      int be1 = __popcll(ebb[0]), be2 = be1 + __popcll(ebb[1]), be3 = be2 + __popcll(ebb[2]);
      int bes[4] = {0, be1, be2, be3};
      int need = 32 - cgt;
      bf16x4 pq;
#pragma unroll
      for (int t = 0; t < 4; t++) {
        int ret = bes[t] + __builtin_amdgcn_mbcnt_hi(
                               (unsigned)(ebb[t] >> 32),
                               __builtin_amdgcn_mbcnt_lo((unsigned)ebb[t], 0));
        bool isg = uk[i][t] > T;
        bool sel = isg || (uk[i][t] == T && ret < need);
        unsigned bits = uk[i][t] ^ ((uk[i][t] >> 15) ? 0x8000u : 0xFFFFu);
        float scv = __uint_as_float(bits << 16);
        float w = sel ? __expf(scv - Tv) : 0.f;
        pq[t] = (__bf16)w;
      }
      *(bf16x4*)&Sb[(row0 + i) * 256 + ((lane << 2) ^ (i << 3))] = pq;
    }
  }
  __syncthreads();

  // ---- O = P @ V via MFMA; wsum via append-ones MFMA (no shfl chains) ----
  f32x4 oacc = {0.f, 0.f, 0.f, 0.f};
  f32x4 wacc = {0.f, 0.f, 0.f, 0.f};
  bf16x8 ones;
#pragma unroll
  for (int j = 0; j < 8; j++) ones[j] = (__bf16)1.0f;
  int prow = ((wave >> 1) << 4) + (lane & 15);   // row 0..63
  int drow = ((wave & 1) << 4) + (lane & 15);    // d 0..31
  int koff = (lane >> 4) << 3;
#pragma unroll
  for (int ks = 0; ks < 8; ks++) {
    bf16x8 pa = *(const bf16x8*)&Sb[prow * 256 + (((ks << 5) + koff) ^ ((prow & 7) << 3))];
    int ck = (ks << 2) + (lane >> 4);
    int cp = (ck + (drow & 7) + ((drow >> 3) << 1)) & 31;
    bf16x8 vb = *(const bf16x8*)&Vt[(drow << 8) + (cp << 3)];
    oacc = __builtin_amdgcn_mfma_f32_16x16x32_bf16(pa, vb, oacc, 0, 0, 0);
    wacc = __builtin_amdgcn_mfma_f32_16x16x32_bf16(pa, ones, wacc, 0, 0, 0);
  }
  {
    int rl = ((wave >> 1) << 4) + ((lane >> 4) << 2);
    float* ob = aout + bm + r * 2048;
#pragma unroll
    for (int reg = 0; reg < 4; reg++) {
      float rinv = __builtin_amdgcn_rcpf(wacc[reg]);
      int rowg = rl + reg;
      ob[(rowg << 5) + ((wave & 1) << 4) + (lane & 15)] = oacc[reg] * rinv;
    }
  }
}

// ---------------------------------------------------------------------------
// K6: t = seq2grid(attn_out) + dwconv5x5(v) + lepe_b, NHWC bf16 out.
// ---------------------------------------------------------------------------
__global__ __launch_bounds__(256) void lepe_kernel(
    const float* __restrict__ ao, const __bf16* __restrict__ v,
    const float* __restrict__ lw, const float* __restrict__ lb,
    __bf16* __restrict__ tout) {
  __shared__ float Ls[144][32];
  __shared__ float Ws[25][32];
  int blk = blockIdx.x;  // 8*8*64
  int b = blk >> 9, m = (blk >> 6) & 7, r = blk & 63;
  int h0 = (r >> 3) << 3, w0 = (r & 7) << 3;
  int tid = threadIdx.x, d = tid & 31;
  size_t bm = (size_t)(b * 8 + m) * 131072;
  for (int i = tid; i < 144 * 32; i += 256) {
    int pos = i >> 5, dd = i & 31;
    int hh = h0 + (pos / 12) - 2, ww = w0 + (pos % 12) - 2;
    float val = 0.f;
    if (hh >= 0 && hh < 64 && ww >= 0 && ww < 64) {
      int r2 = ((hh >> 3) << 3) | (ww >> 3), s2 = ((hh & 7) << 3) | (ww & 7);
      val = (float)v[bm + r2 * 2048 + s2 * 32 + dd];
    }
    Ls[pos][dd] = val;
  }
  for (int i = tid; i < 800; i += 256) {
    int tap = i >> 5, dd = i & 31;
    Ws[tap][dd] = lw[(m * 32 + dd) * 25 + tap];
  }
  __syncthreads();
  int c = m * 32 + d;
  float bias = lb[c];
  for (int j = 0; j < 8; j++) {
    int p = (tid >> 5) + (j << 3);
    int ph = p >> 3, pww = p & 7;
    float acc = bias;
#pragma unroll
    for (int dh = 0; dh < 5; dh++)
#pragma unroll
      for (int dw = 0; dw < 5; dw++)
        acc += Ls[(ph + dh) * 12 + (pww + dw)][d] * Ws[dh * 5 + dw][d];
    acc += ao[bm + r * 2048 + p * 32 + d];
    tout[((size_t)(b * 4096 + (h0 + ph) * 64 + (w0 + pww))) * 256 + c] =
        (__bf16)acc;
  }
}

extern "C" void kernel_launch(void* const* d_in, const int* in_sizes, int n_in,
                              void* d_out, int out_size, void* d_ws, size_t ws_size,
                              hipStream_t stream) {
  (void)in_sizes; (void)n_in; (void)out_size; (void)ws_size;
  const float* x      = (const float*)d_in[0];
  const float* pos_w  = (const float*)d_in[1];
  const float* pos_b  = (const float*)d_in[2];
  const float* ln1_g  = (const float*)d_in[3];
  const float* ln1_b  = (const float*)d_in[4];
  const float* qkv_w  = (const float*)d_in[5];
  const float* qkv_b  = (const float*)d_in[6];
  const float* lepe_w = (const float*)d_in[7];
  const float* lepe_b = (const float*)d_in[8];
  const float* out_w  = (const float*)d_in[9];
  const float* out_b  = (const float*)d_in[10];
  const float* ln2_g  = (const float*)d_in[11];
  const float* ln2_b  = (const float*)d_in[12];
  const float* mlp_w1 = (const float*)d_in[13];
  const float* mlp_b1 = (const float*)d_in[14];
  const float* mlp_w2 = (const float*)d_in[15];
  const float* mlp_b2 = (const float*)d_in[16];

  float* ws = (float*)d_ws;
  const size_t P = 8ull * 4096 * 256;  // 8.39M floats
  size_t off = 0;
  float* xa = ws + off; off += P;        // residual stream NHWC fp32
  float* q  = ws + off; off += P;        // xt scratch; later attn OUT (fp32)
  __bf16* k = (__bf16*)(ws + off); off += P / 2;   // k bf16 seq
  __bf16* v = (__bf16*)(ws + off); off += P / 2;   // v bf16 seq
  __bf16* lnb = (__bf16*)(ws + off); off += P / 2; // bf16 activations
  __bf16* hb  = (__bf16*)(ws + off); off += 12582912; // MLP hidden [32768][768] bf16
  __bf16* wq  = (__bf16*)(ws + off); off += 98304;   // [768][256]
  __bf16* wo  = (__bf16*)(ws + off); off += 32768;   // [256][256]
  __bf16* w1t = (__bf16*)(ws + off); off += 98304;   // [768][256]
  __bf16* w2t = (__bf16*)(ws + off); off += 98304;   // [256][768]
  float* qr  = ws + off; off += 131072;
  float* kr  = ws + off; off += 131072;
  float* lnm = ws + off; off += 131072;
  int* ridx  = (int*)(ws + off);

  // q bf16 (pre-scaled) aliases hb: hb is dead until the MLP (step 10),
  // qbf is dead after attn (step 6) — no temporal overlap.
  __bf16* qbf = hb;

  // 0) weight prep
  wprep_kernel<<<768, 256, 0, stream>>>(qkv_w, out_w, mlp_w1, mlp_w2,
                                        wq, wo, w1t, w2t);
  // 1) NCHW -> NHWC transpose of x into q (scratch)
  transpose_kernel<<<dim3(64, 4, 8), 256, 0, stream>>>(x, q, 256, 4096);
  // 2) pos dwconv + residual
  posconv_kernel<<<2048, 256, 0, stream>>>(q, pos_w, pos_b, xa);
  // 3) FUSED LN1 + region-mean (single xa read pass)
  ln1mean_kernel<<<512, 256, 0, stream>>>(xa, ln1_g, ln1_b, lnb, lnm);
  // 4) routing path, fp32-exact (v2: 128 blocks)
  qkr_kernel<<<512, 256, 0, stream>>>(lnm, qkv_w, qkv_b, qr, kr);
  routing_kernel<<<dim3(16, 8), 256, 0, stream>>>(qr, kr, ridx);
  // 5) qkv GEMM (MFMA bf16): q bf16 pre-scaled, k/v bf16 seq layout
  mfma_gemm<0><<<dim3(6, 256), 256, 0, stream>>>(
      lnb, wq, qkv_b, nullptr, nullptr, nullptr, qbf, k, v, 768, 256, 0);
  // 6) sparse attention (MFMA, 512 thr; writes fp32 into q)
  attn_kernel<<<4096, 512, 0, stream>>>(qbf, q, k, v, ridx);
  // 7) seq2grid + LEPE dwconv5x5 -> lnb (bf16 t)
  lepe_kernel<<<4096, 256, 0, stream>>>(q, v, lepe_w, lepe_b, lnb);
  // 8+9) FUSED out projection + residual + LN2 (writes xa fp32 and lnb bf16)
  gemm_ln_kernel<<<256, 512, 0, stream>>>(lnb, wo, out_b, xa, ln2_g, ln2_b,
                                          lnb);
  // 10) MLP single pass; mlp2 writes d_out NCHW directly (fused transpose)
  mfma_gemm<2><<<dim3(6, 256), 256, 0, stream>>>(
      lnb, w1t, mlp_b1, nullptr, nullptr, hb, nullptr, nullptr, nullptr,
      768, 256, 0);
  mfma_gemm<3><<<dim3(2, 256), 256, 0, stream>>>(
      hb, w2t, mlp_b2, xa, (float*)d_out, nullptr, nullptr, nullptr, nullptr,
      256, 768, 0);
}

// Round 8
// 534.972 us; speedup vs baseline: 1.0388x; 1.0388x over previous
//
#include <hip/hip_runtime.h>
#include <cmath>

// Problem constants
// B=8, C=256, H=W=64, HW=4096, NT=32768 tokens
// heads M=8, head dim D=32, regions NR=64 (8x8 of 8x8), RSQ=64, TOPK=4, KSEL=32

typedef __bf16 bf16x8 __attribute__((ext_vector_type(8)));
typedef __bf16 bf16x4 __attribute__((ext_vector_type(4)));
typedef float f32x4 __attribute__((ext_vector_type(4)));
typedef float f32x2 __attribute__((ext_vector_type(2)));
typedef unsigned short us4 __attribute__((ext_vector_type(4)));

__device__ __forceinline__ void async_copy16(const __bf16* g, __bf16* l) {
  __builtin_amdgcn_global_load_lds(
      (const __attribute__((address_space(1))) void*)g,
      (__attribute__((address_space(3))) void*)l, 16, 0, 0);
}

// ---------------------------------------------------------------------------
// Tiled transpose: per batch, src [R][Cc] -> dst [Cc][R]. 64x64 tiles.
// ---------------------------------------------------------------------------
__global__ __launch_bounds__(256) void transpose_kernel(
    const float* __restrict__ src, float* __restrict__ dst, int R, int Cc) {
  __shared__ float T[64][65];
  int b = blockIdx.z;
  int r0 = blockIdx.y * 64, c0 = blockIdx.x * 64;
  const float* S = src + (size_t)b * R * Cc;
  float* D = dst + (size_t)b * R * Cc;
  int lane = threadIdx.x & 63, wq = threadIdx.x >> 6;
#pragma unroll
  for (int j = 0; j < 16; j++) {
    int rr = wq + j * 4;
    T[rr][lane] = S[(size_t)(r0 + rr) * Cc + c0 + lane];
  }
  __syncthreads();
#pragma unroll
  for (int j = 0; j < 16; j++) {
    int cc = wq + j * 4;
    D[(size_t)(c0 + cc) * R + r0 + lane] = T[lane][cc];
  }
}

// ---------------------------------------------------------------------------
// K1: xa = xt + dwconv3x3(xt,pos), all NHWC.
// ---------------------------------------------------------------------------
__global__ __launch_bounds__(256) void posconv_kernel(
    const float* __restrict__ xt, const float* __restrict__ pw,
    const float* __restrict__ pb, float* __restrict__ xa) {
  __shared__ float Ls[100][64];
  __shared__ float Ws[9][64];
  int blk = blockIdx.x;  // 8*64*4
  int b = blk >> 8, r = (blk >> 2) & 63, cg = blk & 3;
  int h0 = (r >> 3) << 3, w0 = (r & 7) << 3;
  int c0 = cg << 6;
  int tid = threadIdx.x, cl = tid & 63;
  const float* src = xt + ((size_t)b * 4096) * 256;
  for (int i = tid; i < 6400; i += 256) {
    int pos = i >> 6, ccl = i & 63;
    int hh = h0 + (pos / 10) - 1, ww = w0 + (pos % 10) - 1;
    float val = 0.f;
    if (hh >= 0 && hh < 64 && ww >= 0 && ww < 64)
      val = src[(size_t)(hh * 64 + ww) * 256 + c0 + ccl];
    Ls[pos][ccl] = val;
  }
  for (int i = tid; i < 576; i += 256) {
    int tap = i >> 6, ccl = i & 63;
    Ws[tap][ccl] = pw[(c0 + ccl) * 9 + tap];
  }
  __syncthreads();
  float bias = pb[c0 + cl];
  for (int j = 0; j < 16; j++) {
    int p = (tid >> 6) + (j << 2);
    int ph = p >> 3, pww = p & 7;
    float acc = bias;
#pragma unroll
    for (int dh = 0; dh < 3; dh++)
#pragma unroll
      for (int dw = 0; dw < 3; dw++)
        acc += Ls[(ph + dh) * 10 + (pww + dw)][cl] * Ws[dh * 3 + dw][cl];
    float xv = Ls[(ph + 1) * 10 + (pww + 1)][cl];
    xa[((size_t)(b * 4096 + (h0 + ph) * 64 + (w0 + pww))) * 256 + c0 + cl] =
        xv + acc;
  }
}

// ---------------------------------------------------------------------------
// FUSED LN1 + region-mean: block per (b, region), 4 waves x 16 tokens.
// ---------------------------------------------------------------------------
__global__ __launch_bounds__(256) void ln1mean_kernel(
    const float* __restrict__ xa, const float* __restrict__ g,
    const float* __restrict__ bb, __bf16* __restrict__ lnb,
    float* __restrict__ lnm) {
  __shared__ float part[4][256];
  int blk = blockIdx.x;  // 8*64
  int b = blk >> 6, r = blk & 63;
  int h0 = (r >> 3) << 3, w0 = (r & 7) << 3;
  int wave = threadIdx.x >> 6, l = threadIdx.x & 63;
  float ga = g[l], gb2 = g[l + 64], gc = g[l + 128], gd = g[l + 192];
  float ba = bb[l], bb2 = bb[l + 64], bc = bb[l + 128], bd = bb[l + 192];
  float a0 = 0.f, a1 = 0.f, a2 = 0.f, a3 = 0.f;
  for (int t = 0; t < 16; t++) {
    int p = wave * 16 + t;
    int h = h0 + (p >> 3), w = w0 + (p & 7);
    size_t tok = (size_t)(b * 4096 + h * 64 + w) * 256;
    const float* row = xa + tok;
    float v0 = row[l], v1 = row[l + 64], v2 = row[l + 128], v3 = row[l + 192];
    float s = v0 + v1 + v2 + v3;
#pragma unroll
    for (int off = 32; off; off >>= 1) s += __shfl_xor(s, off);
    float mu = s * (1.f / 256.f);
    float d0 = v0 - mu, d1 = v1 - mu, d2 = v2 - mu, d3 = v3 - mu;
    float sq = d0 * d0 + d1 * d1 + d2 * d2 + d3 * d3;
#pragma unroll
    for (int off = 32; off; off >>= 1) sq += __shfl_xor(sq, off);
    float rstd = rsqrtf(sq * (1.f / 256.f) + 1e-6f);
    float n0 = d0 * rstd, n1 = d1 * rstd, n2 = d2 * rstd, n3 = d3 * rstd;
    __bf16* o = lnb + tok;
    o[l]       = (__bf16)(n0 * ga + ba);
    o[l + 64]  = (__bf16)(n1 * gb2 + bb2);
    o[l + 128] = (__bf16)(n2 * gc + bc);
    o[l + 192] = (__bf16)(n3 * gd + bd);
    a0 += n0; a1 += n1; a2 += n2; a3 += n3;
  }
  part[wave][l] = a0; part[wave][l + 64] = a1;
  part[wave][l + 128] = a2; part[wave][l + 192] = a3;
  __syncthreads();
  if (wave == 0) {
    for (int ch = l; ch < 256; ch += 64) {
      float s2 = part[0][ch] + part[1][ch] + part[2][ch] + part[3][ch];
      lnm[(size_t)(b * 64 + r) * 256 + ch] = g[ch] * (s2 * (1.f / 64.f)) + bb[ch];
    }
  }
}

// ---------------------------------------------------------------------------
// Weight prep: bf16-convert qkv_w [768][256], out_w [256][256],
// transpose+convert mlp_w1 [256][768]->[768][256], mlp_w2 [768][256]->[256][768]
// ---------------------------------------------------------------------------
__global__ __launch_bounds__(256) void wprep_kernel(
    const float* __restrict__ qkv_w, const float* __restrict__ out_w,
    const float* __restrict__ w1, const float* __restrict__ w2,
    __bf16* __restrict__ wq, __bf16* __restrict__ wo,
    __bf16* __restrict__ w1t, __bf16* __restrict__ w2t) {
  int i = blockIdx.x * 256 + threadIdx.x;
  if (i < 196608) wq[i] = (__bf16)qkv_w[i];
  if (i < 65536) wo[i] = (__bf16)out_w[i];
  if (i < 196608) {  // w1t[n][k] = w1[k][n], n<768, k<256
    int n = i >> 8, k2 = i & 255;
    w1t[i] = (__bf16)w1[k2 * 768 + n];
  }
  if (i < 196608) {  // w2t[n][k] = w2[k][n], n<256, k<768
    int n = i / 768, k2 = i % 768;
    w2t[i] = (__bf16)w2[k2 * 256 + n];
  }
}

// ---------------------------------------------------------------------------
// MFMA bf16 GEMM: C[row][col] = epi( sum_k A[row][k]*Bw[col][k] + bias[col] )
// EPI: 0 = scatter to q(bf16, pre-scaled 1/16)/k,v(bf16) seq layout;
//      2 = gelu -> bf16; 3 = res+val written NCHW fp32
// ---------------------------------------------------------------------------
template <int EPI>
__global__ __launch_bounds__(256) void mfma_gemm(
    const __bf16* __restrict__ A, const __bf16* __restrict__ Bw,
    const float* __restrict__ bias, const float* __restrict__ res,
    float* __restrict__ out, __bf16* __restrict__ outb,
    __bf16* __restrict__ qd, __bf16* __restrict__ kd, __bf16* __restrict__ vd,
    int N, int K, int row0) {
  __shared__ __bf16 Asl[128 * 32];
  __shared__ __bf16 Bsl[128 * 32];
  int tid = threadIdx.x;
  int lane = tid & 63, wave = tid >> 6;
  int m0 = blockIdx.y * 128, n0 = blockIdx.x * 128;
  int wr = (wave >> 1) * 64, wc = (wave & 1) * 64;

  f32x4 acc[4][4];
  f32x4 z = {0.f, 0.f, 0.f, 0.f};
#pragma unroll
  for (int i = 0; i < 4; i++)
#pragma unroll
    for (int j = 0; j < 4; j++) acc[i][j] = z;

  int srow = (lane >> 2);          // 0..15
  int skoff = (lane & 3) * 8;      // 0,8,16,24
  for (int k0 = 0; k0 < K; k0 += 32) {
#pragma unroll
    for (int j = 0; j < 2; j++) {
      int rbase = wave * 32 + j * 16;
      const __bf16* ga = A + (size_t)(m0 + rbase + srow) * K + k0 + skoff;
      const __bf16* gb = Bw + (size_t)(n0 + rbase + srow) * K + k0 + skoff;
      async_copy16(ga, &Asl[rbase * 32]);
      async_copy16(gb, &Bsl[rbase * 32]);
    }
    __syncthreads();
    bf16x8 af[4], bf[4];
#pragma unroll
    for (int t = 0; t < 4; t++) {
      af[t] = *(const bf16x8*)&Asl[(wr + t * 16 + (lane & 15)) * 32 + (lane >> 4) * 8];
      bf[t] = *(const bf16x8*)&Bsl[(wc + t * 16 + (lane & 15)) * 32 + (lane >> 4) * 8];
    }
#pragma unroll
    for (int ti = 0; ti < 4; ti++)
#pragma unroll
      for (int tj = 0; tj < 4; tj++)
        acc[ti][tj] = __builtin_amdgcn_mfma_f32_16x16x32_bf16(
            af[ti], bf[tj], acc[ti][tj], 0, 0, 0);
    __syncthreads();
  }
  // epilogue: C/D layout col=lane&15, row=(lane>>4)*4+reg
#pragma unroll
  for (int ti = 0; ti < 4; ti++) {
#pragma unroll
    for (int tj = 0; tj < 4; tj++) {
      int colg = n0 + wc + tj * 16 + (lane & 15);
      float bv = bias[colg];
#pragma unroll
      for (int reg = 0; reg < 4; reg++) {
        int rowg = m0 + wr + ti * 16 + (lane >> 4) * 4 + reg;
        float val = acc[ti][tj][reg] + bv;
        if (EPI == 0) {
          int tns = colg >> 8, cc = colg & 255, m = cc >> 5, d = cc & 31;
          int grow = row0 + rowg;
          int b = grow >> 12, hw = grow & 4095, h = hw >> 6, w = hw & 63;
          int r = ((h >> 3) << 3) | (w >> 3), s2 = ((h & 7) << 3) | (w & 7);
          size_t addr = (size_t)(b * 8 + m) * 131072 + r * 2048 + s2 * 32 + d;
          if (tns == 0) qd[addr] = (__bf16)(val * 0.0625f);  // fold scale C^-0.5
          else if (tns == 1) kd[addr] = (__bf16)val;
          else vd[addr] = (__bf16)val;
        } else if (EPI == 2) {
          outb[(size_t)rowg * N + colg] =
              (__bf16)(0.5f * val * (1.f + erff(val * 0.70710678118654752f)));
        } else {
          int grow = row0 + rowg;
          int b = grow >> 12, hw = grow & 4095;
          out[(size_t)(b * 256 + colg) * 4096 + hw] =
              res[(size_t)grow * 256 + colg] + val;
        }
      }
    }
  }
}

// ---------------------------------------------------------------------------
// FUSED out-projection + residual + LN2: 512 thr, 128x256 tile (full C rows),
// grid = 256 row-blocks. Replaces mfma_gemm<1> + ln_kernel.
// ---------------------------------------------------------------------------
__global__ __launch_bounds__(512) void gemm_ln_kernel(
    const __bf16* A, const __bf16* __restrict__ Bw,
    const float* __restrict__ bias, float* __restrict__ xa,
    const float* __restrict__ g2, const float* __restrict__ b2,
    __bf16* lnbo) {
  __shared__ __bf16 Asl[128 * 32];
  __shared__ __bf16 Bsl[256 * 32];
  __shared__ float part1[128][4];
  __shared__ float part2[128][4];
  __shared__ float muv[128];
  __shared__ float rsv[128];
  int tid = threadIdx.x;
  int lane = tid & 63, wave = tid >> 6;
  int m0 = blockIdx.x * 128;
  int wr = (wave >> 2) * 64, wc = (wave & 3) * 64;

  f32x4 acc[4][4];
  f32x4 z = {0.f, 0.f, 0.f, 0.f};
#pragma unroll
  for (int i = 0; i < 4; i++)
#pragma unroll
    for (int j = 0; j < 4; j++) acc[i][j] = z;

  int srow = lane >> 2, skoff = (lane & 3) * 8;
  for (int k0 = 0; k0 < 256; k0 += 32) {
#pragma unroll
    for (int j = 0; j < 3; j++) {
      int seg = wave + 8 * j;
      if (seg < 8) {
        const __bf16* ga = A + (size_t)(m0 + seg * 16 + srow) * 256 + k0 + skoff;
        async_copy16(ga, &Asl[seg * 16 * 32]);
      } else {
        const __bf16* gb =
            Bw + (size_t)((seg - 8) * 16 + srow) * 256 + k0 + skoff;
        async_copy16(gb, &Bsl[(seg - 8) * 16 * 32]);
      }
    }
    __syncthreads();
    bf16x8 af[4], bf[4];
#pragma unroll
    for (int t = 0; t < 4; t++) {
      af[t] = *(const bf16x8*)&Asl[(wr + t * 16 + (lane & 15)) * 32 + (lane >> 4) * 8];
      bf[t] = *(const bf16x8*)&Bsl[(wc + t * 16 + (lane & 15)) * 32 + (lane >> 4) * 8];
    }
#pragma unroll
    for (int ti = 0; ti < 4; ti++)
#pragma unroll
      for (int tj = 0; tj < 4; tj++)
        acc[ti][tj] = __builtin_amdgcn_mfma_f32_16x16x32_bf16(
            af[ti], bf[tj], acc[ti][tj], 0, 0, 0);
    __syncthreads();
  }

  // epilogue phase 1: v = acc + bias + res; write xa; accumulate partials
  float s1[16], s2v[16];
#pragma unroll
  for (int k = 0; k < 16; k++) { s1[k] = 0.f; s2v[k] = 0.f; }
#pragma unroll
  for (int tj = 0; tj < 4; tj++) {
    int colg = wc + tj * 16 + (lane & 15);
    float bv = bias[colg];
#pragma unroll
    for (int ti = 0; ti < 4; ti++) {
#pragma unroll
      for (int reg = 0; reg < 4; reg++) {
        int rowg = m0 + wr + ti * 16 + (lane >> 4) * 4 + reg;
        float v = acc[ti][tj][reg] + bv + xa[(size_t)rowg * 256 + colg];
        xa[(size_t)rowg * 256 + colg] = v;
        acc[ti][tj][reg] = v;  // keep for phase 2
        s1[ti * 4 + reg] += v;
        s2v[ti * 4 + reg] += v * v;
      }
    }
  }
  // reduce over the 16-lane col group (lane&15)
#pragma unroll
  for (int off = 1; off < 16; off <<= 1) {
#pragma unroll
    for (int k = 0; k < 16; k++) {
      s1[k] += __shfl_xor(s1[k], off);
      s2v[k] += __shfl_xor(s2v[k], off);
    }
  }
  if ((lane & 15) == 0) {
    int q = lane >> 4;
#pragma unroll
    for (int k = 0; k < 16; k++) {
      int rowl = wr + (k >> 2) * 16 + q * 4 + (k & 3);
      part1[rowl][wave & 3] = s1[k];
      part2[rowl][wave & 3] = s2v[k];
    }
  }
  __syncthreads();
  if (tid < 128) {
    float S1 = part1[tid][0] + part1[tid][1] + part1[tid][2] + part1[tid][3];
    float S2 = part2[tid][0] + part2[tid][1] + part2[tid][2] + part2[tid][3];
    float mu = S1 * (1.f / 256.f);
    float var = S2 * (1.f / 256.f) - mu * mu;
    muv[tid] = mu;
    rsv[tid] = rsqrtf(var + 1e-6f);
  }
  __syncthreads();
  // phase 2: lnb = (v - mu)*rstd*g + b
#pragma unroll
  for (int tj = 0; tj < 4; tj++) {
    int colg = wc + tj * 16 + (lane & 15);
    float gg = g2[colg], bb = b2[colg];
#pragma unroll
    for (int ti = 0; ti < 4; ti++) {
#pragma unroll
      for (int reg = 0; reg < 4; reg++) {
        int rowl = wr + ti * 16 + (lane >> 4) * 4 + reg;
        int rowg = m0 + rowl;
        lnbo[(size_t)rowg * 256 + colg] =
            (__bf16)((acc[ti][tj][reg] - muv[rowl]) * rsv[rowl] * gg + bb);
      }
    }
  }
}

__global__ __launch_bounds__(256) void qkr_kernel(
    const float* __restrict__ lnm, const float* __restrict__ qkv_w,
    const float* __restrict__ qkv_b, float* __restrict__ qr,
    float* __restrict__ kr) {
  __shared__ float xm[256];
  int br = blockIdx.x, c = threadIdx.x;
  xm[c] = lnm[(size_t)br * 256 + c];
  __syncthreads();
  const float* wqp = qkv_w + (size_t)c * 256;
  const float* wkp = qkv_w + (size_t)(256 + c) * 256;
  float aq = 0.f, ak = 0.f;
  for (int k2 = 0; k2 < 256; k2++) {
    float xv = xm[k2];
    aq += wqp[k2] * xv; ak += wkp[k2] * xv;
  }
  qr[(size_t)br * 256 + c] = aq + qkv_b[c];
  kr[(size_t)br * 256 + c] = ak + qkv_b[256 + c];
}

// ---------------------------------------------------------------------------
// Routing v2: grid (16 row-groups, 8 batches), 4 waves/block.
// ---------------------------------------------------------------------------
__global__ __launch_bounds__(256) void routing_kernel(
    const float* __restrict__ qr, const float* __restrict__ kr,
    int* __restrict__ idxout) {
  __shared__ float Ar[4][64];
  int b = blockIdx.y, rg = blockIdx.x;
  int tid = threadIdx.x;
  int lane = tid & 63, wave = tid >> 6;
  int i = (rg << 2) + wave;
  const float* qrow = qr + (size_t)(b * 64 + i) * 256;
  const float* krow = kr + (size_t)(b * 64 + lane) * 256;
  float acc = 0.f;
  for (int c = 0; c < 256; c++) acc += qrow[c] * krow[c];
  Ar[wave][lane] = acc;
  __syncthreads();
  if (lane == 0) {
    float v0 = -INFINITY, v1 = -INFINITY, v2 = -INFINITY, v3 = -INFINITY;
    int i0 = 0, i1 = 0, i2 = 0, i3 = 0;
    for (int j = 0; j < 64; j++) {
      float s = Ar[wave][j];
      if (s > v0)      { v3=v2;i3=i2; v2=v1;i2=i1; v1=v0;i1=i0; v0=s;i0=j; }
      else if (s > v1) { v3=v2;i3=i2; v2=v1;i2=i1; v1=s;i1=j; }
      else if (s > v2) { v3=v2;i3=i2; v2=s;i2=j; }
      else if (s > v3) { v3=s;i3=j; }
    }
    int* op = idxout + (b * 64 + i) * 4;
    op[0] = i0; op[1] = i1; op[2] = i2; op[3] = i3;
  }
}

// ---------------------------------------------------------------------------
// Attention per (b,m,r) — MFMA, 512 threads / 8 waves, chunks concurrent.
// R8: wsum via append-ones MFMA during PV (kept from R7 — removes shfl
//     chains + wsum_l LDS round-trip). Radix loop restored to FIXED 16
//     fully-unrolled iterations (R7's early-exit break serialized the 8
//     per-row ballot chains at a per-bit scalar join — 15us regression).
// LDS: Vt 16K (rotation) + Sb[64][256] 32K = 48.1KB -> 3 blocks/CU, 24 w/CU.
// ---------------------------------------------------------------------------
__global__ __launch_bounds__(512, 6) void attn_kernel(
    const __bf16* __restrict__ qbf, float* __restrict__ aout,
    const __bf16* __restrict__ kbuf, const __bf16* __restrict__ vbuf,
    const int* __restrict__ idx) {
  __shared__ __bf16 Vt[32 * 256];   // rotation layout
  __shared__ __bf16 Sb[64 * 256];   // [row][key ^ ((row&7)<<3)] : S then P
  int blk = blockIdx.x; int r = blk & 63; int m = (blk >> 6) & 7; int b = blk >> 9;
  int tid = threadIdx.x;
  int lane = tid & 63, wave = tid >> 6;   // wave 0..7
  const int* ip = idx + (b * 64 + r) * 4;
  size_t bm = (size_t)(b * 8 + m) * 131072;
  int rgs[4] = {ip[0], ip[1], ip[2], ip[3]};

  // ---- stage V -> Vt (rotation layout), conflict-free b16 writes ----
  {
    int tid2 = tid & 255;
    int rid = tid >> 8;               // 0..1
    int s = tid2 >> 2, g8 = tid2 & 3; // key-in-region, d-chunk
#pragma unroll
    for (int t = 0; t < 2; t++) {
      int rgi = (t << 1) | rid;
      int rlo = (rgi & 1) ? rgs[1] : rgs[0];
      int rhi = (rgi & 1) ? rgs[3] : rgs[2];
      int rgv = (rgi & 2) ? rhi : rlo;
      const uint4* sv = (const uint4*)(vbuf + bm + (size_t)rgv * 2048);
      uint4 vw = sv[tid2];
      int kk = (rgi << 6) | s;
      int ck = kk >> 3, klo = kk & 7;
      union { uint4 u; __bf16 h[8]; } vu; vu.u = vw;
#pragma unroll
      for (int j = 0; j < 8; j++) {
        int d = (g8 << 3) + j;
        int cp = (ck + j + (g8 << 1)) & 31;   // (ck + (d&7) + 2*(d>>3)) & 31
        Vt[(d << 8) + (cp << 3) + klo] = vu.h[j];
      }
    }
  }

  // ---- Q fragments for this wave's chunk (c = wave>>2) ----
  int chnk = wave >> 2;
  const __bf16* qb = qbf + bm + r * 2048;
  bf16x8 qf[2];
#pragma unroll
  for (int rtl = 0; rtl < 2; rtl++) {
    int rt = (chnk << 1) + rtl;
    qf[rtl] = *(const bf16x8*)(qb + ((rt * 16 + (lane & 15)) << 5) + ((lane >> 4) << 3));
  }

  // ---- K fragments direct from global: region rgs[wave&3] ----
  bf16x8 kf[4];
  {
    int rw0 = (wave & 1) ? rgs[1] : rgs[0];
    int rw1 = (wave & 1) ? rgs[3] : rgs[2];
    int rgw = (wave & 2) ? rw1 : rw0;
    const __bf16* kb = kbuf + bm + (size_t)rgw * 2048;
#pragma unroll
    for (int kt4 = 0; kt4 < 4; kt4++)
      kf[kt4] = *(const bf16x8*)(kb + ((kt4 * 16 + (lane & 15)) << 5) + ((lane >> 4) << 3));
  }

  // ---- S^T = K @ Q^T: wave covers (chunk, region) pair ----
#pragma unroll
  for (int kt4 = 0; kt4 < 4; kt4++) {
    int kt = ((wave & 3) << 2) + kt4;   // global key-tile
#pragma unroll
    for (int rtl = 0; rtl < 2; rtl++) {
      f32x4 st = {0.f, 0.f, 0.f, 0.f};
      st = __builtin_amdgcn_mfma_f32_16x16x32_bf16(kf[kt4], qf[rtl], st, 0, 0, 0);
      // D: M(key)=kt*16+4*(lane>>4)+reg ; N(row)=chunk*32+rtl*16+(lane&15)
      int row = (chnk << 5) + (rtl << 4) + (lane & 15);   // 0..63
      int key0 = (kt << 4) + ((lane >> 4) << 2);
      bf16x4 sv4;
#pragma unroll
      for (int j = 0; j < 4; j++) sv4[j] = (__bf16)st[j];
      *(bf16x4*)&Sb[row * 256 + (key0 ^ ((row & 7) << 3))] = sv4;
    }
  }
  __syncthreads();

  // ---- select top-32 per row: rows 8*wave .. 8*wave+7 (fixed 16 bits) ----
  {
    int row0 = wave << 3;
    unsigned uk[8][4];
#pragma unroll
    for (int i = 0; i < 8; i++) {
      us4 q4 = *(const us4*)&Sb[(row0 + i) * 256 + ((lane << 2) ^ (i << 3))];
#pragma unroll
      for (int t = 0; t < 4; t++) {
        unsigned bits = q4[t];
        uk[i][t] = (bits ^ ((0u - (bits >> 15)) | 0x8000u)) & 0xFFFFu;
      }
    }
    unsigned p[8];
#pragma unroll
    for (int i = 0; i < 8; i++) p[i] = 0;
#pragma unroll
    for (int bit = 15; bit >= 0; --bit) {
      unsigned msk = 1u << bit;
#pragma unroll
      for (int i = 0; i < 8; i++) {
        unsigned cc = p[i] | msk;
        int n = __popcll(__ballot(uk[i][0] >= cc)) + __popcll(__ballot(uk[i][1] >= cc)) +
                __popcll(__ballot(uk[i][2] >= cc)) + __popcll(__ballot(uk[i][3] >= cc));
        if (n >= 32) p[i] = cc;
      }
    }
#pragma unroll
    for (int i = 0; i < 8; i++) {
      unsigned T = p[i];
      unsigned ub = T << 16;
      unsigned tb = (ub & 0x80000000u) ? (ub ^ 0x80000000u) : ~ub;
      float Tv = __uint_as_float(tb);
      unsigned long long gbb[4], ebb[4];
#pragma unroll
      for (int t = 0; t < 4; t++) {
        gbb[t] = __ballot(uk[i][t] > T);
        ebb[t] = __ballot(uk[i][t] == T);
      }
      int cgt = __popcll(gbb[0]) + __popcll(gbb[1]) + __popcll(gbb[2]) + __popcll(gbb[3]);
      int be1 = __popcll(ebb[0]), be2 = be1 + __popcll(ebb[1]), be3 = be2 + __popcll(ebb[2]);
      int bes[4] = {0, be1, be2, be3};
      int need = 32 - cgt;
      bf16x4 pq;
#pragma unroll
      for (int t = 0; t < 4; t++) {
        int ret = bes[t] + __builtin_amdgcn_mbcnt_hi(
                               (unsigned)(ebb[t] >> 32),
                               __builtin_amdgcn_mbcnt_lo((unsigned)ebb[t], 0));
        bool isg = uk[i][t] > T;
        bool sel = isg || (uk[i][t] == T && ret < need);
        unsigned bits = uk[i][t] ^ ((uk[i][t] >> 15) ? 0x8000u : 0xFFFFu);
        float scv = __uint_as_float(bits << 16);
        float w = sel ? __expf(scv - Tv) : 0.f;
        pq[t] = (__bf16)w;
      }
      *(bf16x4*)&Sb[(row0 + i) * 256 + ((lane << 2) ^ (i << 3))] = pq;
    }
  }
  __syncthreads();

  // ---- O = P @ V via MFMA; wsum via append-ones MFMA (no shfl chains) ----
  f32x4 oacc = {0.f, 0.f, 0.f, 0.f};
  f32x4 wacc = {0.f, 0.f, 0.f, 0.f};
  bf16x8 ones;
#pragma unroll
  for (int j = 0; j < 8; j++) ones[j] = (__bf16)1.0f;
  int prow = ((wave >> 1) << 4) + (lane & 15);   // row 0..63
  int drow = ((wave & 1) << 4) + (lane & 15);    // d 0..31
  int koff = (lane >> 4) << 3;
#pragma unroll
  for (int ks = 0; ks < 8; ks++) {
    bf16x8 pa = *(const bf16x8*)&Sb[prow * 256 + (((ks << 5) + koff) ^ ((prow & 7) << 3))];
    int ck = (ks << 2) + (lane >> 4);
    int cp = (ck + (drow & 7) + ((drow >> 3) << 1)) & 31;
    bf16x8 vb = *(const bf16x8*)&Vt[(drow << 8) + (cp << 3)];
    oacc = __builtin_amdgcn_mfma_f32_16x16x32_bf16(pa, vb, oacc, 0, 0, 0);
    wacc = __builtin_amdgcn_mfma_f32_16x16x32_bf16(pa, ones, wacc, 0, 0, 0);
  }
  {
    int rl = ((wave >> 1) << 4) + ((lane >> 4) << 2);
    float* ob = aout + bm + r * 2048;
#pragma unroll
    for (int reg = 0; reg < 4; reg++) {
      float rinv = __builtin_amdgcn_rcpf(wacc[reg]);
      int rowg = rl + reg;
      ob[(rowg << 5) + ((wave & 1) << 4) + (lane & 15)] = oacc[reg] * rinv;
    }
  }
}

// ---------------------------------------------------------------------------
// K6: t = seq2grid(attn_out) + dwconv5x5(v) + lepe_b, NHWC bf16 out.
// ---------------------------------------------------------------------------
__global__ __launch_bounds__(256) void lepe_kernel(
    const float* __restrict__ ao, const __bf16* __restrict__ v,
    const float* __restrict__ lw, const float* __restrict__ lb,
    __bf16* __restrict__ tout) {
  __shared__ float Ls[144][32];
  __shared__ float Ws[25][32];
  int blk = blockIdx.x;  // 8*8*64
  int b = blk >> 9, m = (blk >> 6) & 7, r = blk & 63;
  int h0 = (r >> 3) << 3, w0 = (r & 7) << 3;
  int tid = threadIdx.x, d = tid & 31;
  size_t bm = (size_t)(b * 8 + m) * 131072;
  for (int i = tid; i < 144 * 32; i += 256) {
    int pos = i >> 5, dd = i & 31;
    int hh = h0 + (pos / 12) - 2, ww = w0 + (pos % 12) - 2;
    float val = 0.f;
    if (hh >= 0 && hh < 64 && ww >= 0 && ww < 64) {
      int r2 = ((hh >> 3) << 3) | (ww >> 3), s2 = ((hh & 7) << 3) | (ww & 7);
      val = (float)v[bm + r2 * 2048 + s2 * 32 + dd];
    }
    Ls[pos][dd] = val;
  }
  for (int i = tid; i < 800; i += 256) {
    int tap = i >> 5, dd = i & 31;
    Ws[tap][dd] = lw[(m * 32 + dd) * 25 + tap];
  }
  __syncthreads();
  int c = m * 32 + d;
  float bias = lb[c];
  for (int j = 0; j < 8; j++) {
    int p = (tid >> 5) + (j << 3);
    int ph = p >> 3, pww = p & 7;
    float acc = bias;
#pragma unroll
    for (int dh = 0; dh < 5; dh++)
#pragma unroll
      for (int dw = 0; dw < 5; dw++)
        acc += Ls[(ph + dh) * 12 + (pww + dw)][d] * Ws[dh * 5 + dw][d];
    acc += ao[bm + r * 2048 + p * 32 + d];
    tout[((size_t)(b * 4096 + (h0 + ph) * 64 + (w0 + pww))) * 256 + c] =
        (__bf16)acc;
  }
}

extern "C" void kernel_launch(void* const* d_in, const int* in_sizes, int n_in,
                              void* d_out, int out_size, void* d_ws, size_t ws_size,
                              hipStream_t stream) {
  (void)in_sizes; (void)n_in; (void)out_size; (void)ws_size;
  const float* x      = (const float*)d_in[0];
  const float* pos_w  = (const float*)d_in[1];
  const float* pos_b  = (const float*)d_in[2];
  const float* ln1_g  = (const float*)d_in[3];
  const float* ln1_b  = (const float*)d_in[4];
  const float* qkv_w  = (const float*)d_in[5];
  const float* qkv_b  = (const float*)d_in[6];
  const float* lepe_w = (const float*)d_in[7];
  const float* lepe_b = (const float*)d_in[8];
  const float* out_w  = (const float*)d_in[9];
  const float* out_b  = (const float*)d_in[10];
  const float* ln2_g  = (const float*)d_in[11];
  const float* ln2_b  = (const float*)d_in[12];
  const float* mlp_w1 = (const float*)d_in[13];
  const float* mlp_b1 = (const float*)d_in[14];
  const float* mlp_w2 = (const float*)d_in[15];
  const float* mlp_b2 = (const float*)d_in[16];

  float* ws = (float*)d_ws;
  const size_t P = 8ull * 4096 * 256;  // 8.39M floats
  size_t off = 0;
  float* xa = ws + off; off += P;        // residual stream NHWC fp32
  float* q  = ws + off; off += P;        // xt scratch; later attn OUT (fp32)
  __bf16* k = (__bf16*)(ws + off); off += P / 2;   // k bf16 seq
  __bf16* v = (__bf16*)(ws + off); off += P / 2;   // v bf16 seq
  __bf16* lnb = (__bf16*)(ws + off); off += P / 2; // bf16 activations
  __bf16* hb  = (__bf16*)(ws + off); off += 12582912; // MLP hidden [32768][768] bf16
  __bf16* wq  = (__bf16*)(ws + off); off += 98304;   // [768][256]
  __bf16* wo  = (__bf16*)(ws + off); off += 32768;   // [256][256]
  __bf16* w1t = (__bf16*)(ws + off); off += 98304;   // [768][256]
  __bf16* w2t = (__bf16*)(ws + off); off += 98304;   // [256][768]
  float* qr  = ws + off; off += 131072;
  float* kr  = ws + off; off += 131072;
  float* lnm = ws + off; off += 131072;
  int* ridx  = (int*)(ws + off);

  // q bf16 (pre-scaled) aliases hb: hb is dead until the MLP (step 10),
  // qbf is dead after attn (step 6) — no temporal overlap.
  __bf16* qbf = hb;

  // 0) weight prep
  wprep_kernel<<<768, 256, 0, stream>>>(qkv_w, out_w, mlp_w1, mlp_w2,
                                        wq, wo, w1t, w2t);
  // 1) NCHW -> NHWC transpose of x into q (scratch)
  transpose_kernel<<<dim3(64, 4, 8), 256, 0, stream>>>(x, q, 256, 4096);
  // 2) pos dwconv + residual
  posconv_kernel<<<2048, 256, 0, stream>>>(q, pos_w, pos_b, xa);
  // 3) FUSED LN1 + region-mean (single xa read pass)
  ln1mean_kernel<<<512, 256, 0, stream>>>(xa, ln1_g, ln1_b, lnb, lnm);
  // 4) routing path, fp32-exact (v2: 128 blocks)
  qkr_kernel<<<512, 256, 0, stream>>>(lnm, qkv_w, qkv_b, qr, kr);
  routing_kernel<<<dim3(16, 8), 256, 0, stream>>>(qr, kr, ridx);
  // 5) qkv GEMM (MFMA bf16): q bf16 pre-scaled, k/v bf16 seq layout
  mfma_gemm<0><<<dim3(6, 256), 256, 0, stream>>>(
      lnb, wq, qkv_b, nullptr, nullptr, nullptr, qbf, k, v, 768, 256, 0);
  // 6) sparse attention (MFMA, 512 thr; writes fp32 into q)
  attn_kernel<<<4096, 512, 0, stream>>>(qbf, q, k, v, ridx);
  // 7) seq2grid + LEPE dwconv5x5 -> lnb (bf16 t)
  lepe_kernel<<<4096, 256, 0, stream>>>(q, v, lepe_w, lepe_b, lnb);
  // 8+9) FUSED out projection + residual + LN2 (writes xa fp32 and lnb bf16)
  gemm_ln_kernel<<<256, 512, 0, stream>>>(lnb, wo, out_b, xa, ln2_g, ln2_b,
                                          lnb);
  // 10) MLP single pass; mlp2 writes d_out NCHW directly (fused transpose)
  mfma_gemm<2><<<dim3(6, 256), 256, 0, stream>>>(
      lnb, w1t, mlp_b1, nullptr, nullptr, hb, nullptr, nullptr, nullptr,
      768, 256, 0);
  mfma_gemm<3><<<dim3(2, 256), 256, 0, stream>>>(
      hb, w2t, mlp_b2, xa, (float*)d_out, nullptr, nullptr, nullptr, nullptr,
      256, 768, 0);
}

// Round 11
// 513.117 us; speedup vs baseline: 1.0830x; 1.0426x over previous
//
#include <hip/hip_runtime.h>
#include <cmath>

// Problem constants
// B=8, C=256, H=W=64, HW=4096, NT=32768 tokens
// heads M=8, head dim D=32, regions NR=64 (8x8 of 8x8), RSQ=64, TOPK=4, KSEL=32

typedef __bf16 bf16x8 __attribute__((ext_vector_type(8)));
typedef __bf16 bf16x4 __attribute__((ext_vector_type(4)));
typedef float f32x4 __attribute__((ext_vector_type(4)));
typedef float f32x2 __attribute__((ext_vector_type(2)));
typedef unsigned short us4 __attribute__((ext_vector_type(4)));

__device__ __forceinline__ void async_copy16(const __bf16* g, __bf16* l) {
  __builtin_amdgcn_global_load_lds(
      (const __attribute__((address_space(1))) void*)g,
      (__attribute__((address_space(3))) void*)l, 16, 0, 0);
}

// ---------------------------------------------------------------------------
// Tiled transpose: per batch, src [R][Cc] -> dst [Cc][R]. 64x64 tiles.
// ---------------------------------------------------------------------------
__global__ __launch_bounds__(256) void transpose_kernel(
    const float* __restrict__ src, float* __restrict__ dst, int R, int Cc) {
  __shared__ float T[64][65];
  int b = blockIdx.z;
  int r0 = blockIdx.y * 64, c0 = blockIdx.x * 64;
  const float* S = src + (size_t)b * R * Cc;
  float* D = dst + (size_t)b * R * Cc;
  int lane = threadIdx.x & 63, wq = threadIdx.x >> 6;
#pragma unroll
  for (int j = 0; j < 16; j++) {
    int rr = wq + j * 4;
    T[rr][lane] = S[(size_t)(r0 + rr) * Cc + c0 + lane];
  }
  __syncthreads();
#pragma unroll
  for (int j = 0; j < 16; j++) {
    int cc = wq + j * 4;
    D[(size_t)(c0 + cc) * R + r0 + lane] = T[lane][cc];
  }
}

// ---------------------------------------------------------------------------
// K1: xa = xt + dwconv3x3(xt,pos), all NHWC.
// ---------------------------------------------------------------------------
__global__ __launch_bounds__(256) void posconv_kernel(
    const float* __restrict__ xt, const float* __restrict__ pw,
    const float* __restrict__ pb, float* __restrict__ xa) {
  __shared__ float Ls[100][64];
  __shared__ float Ws[9][64];
  int blk = blockIdx.x;  // 8*64*4
  int b = blk >> 8, r = (blk >> 2) & 63, cg = blk & 3;
  int h0 = (r >> 3) << 3, w0 = (r & 7) << 3;
  int c0 = cg << 6;
  int tid = threadIdx.x, cl = tid & 63;
  const float* src = xt + ((size_t)b * 4096) * 256;
  for (int i = tid; i < 6400; i += 256) {
    int pos = i >> 6, ccl = i & 63;
    int hh = h0 + (pos / 10) - 1, ww = w0 + (pos % 10) - 1;
    float val = 0.f;
    if (hh >= 0 && hh < 64 && ww >= 0 && ww < 64)
      val = src[(size_t)(hh * 64 + ww) * 256 + c0 + ccl];
    Ls[pos][ccl] = val;
  }
  for (int i = tid; i < 576; i += 256) {
    int tap = i >> 6, ccl = i & 63;
    Ws[tap][ccl] = pw[(c0 + ccl) * 9 + tap];
  }
  __syncthreads();
  float bias = pb[c0 + cl];
  for (int j = 0; j < 16; j++) {
    int p = (tid >> 6) + (j << 2);
    int ph = p >> 3, pww = p & 7;
    float acc = bias;
#pragma unroll
    for (int dh = 0; dh < 3; dh++)
#pragma unroll
      for (int dw = 0; dw < 3; dw++)
        acc += Ls[(ph + dh) * 10 + (pww + dw)][cl] * Ws[dh * 3 + dw][cl];
    float xv = Ls[(ph + 1) * 10 + (pww + 1)][cl];
    xa[((size_t)(b * 4096 + (h0 + ph) * 64 + (w0 + pww))) * 256 + c0 + cl] =
        xv + acc;
  }
}

// ---------------------------------------------------------------------------
// FUSED LN1 + region-mean: block per (b, region), 4 waves x 16 tokens.
// ---------------------------------------------------------------------------
__global__ __launch_bounds__(256) void ln1mean_kernel(
    const float* __restrict__ xa, const float* __restrict__ g,
    const float* __restrict__ bb, __bf16* __restrict__ lnb,
    float* __restrict__ lnm) {
  __shared__ float part[4][256];
  int blk = blockIdx.x;  // 8*64
  int b = blk >> 6, r = blk & 63;
  int h0 = (r >> 3) << 3, w0 = (r & 7) << 3;
  int wave = threadIdx.x >> 6, l = threadIdx.x & 63;
  float ga = g[l], gb2 = g[l + 64], gc = g[l + 128], gd = g[l + 192];
  float ba = bb[l], bb2 = bb[l + 64], bc = bb[l + 128], bd = bb[l + 192];
  float a0 = 0.f, a1 = 0.f, a2 = 0.f, a3 = 0.f;
  for (int t = 0; t < 16; t++) {
    int p = wave * 16 + t;
    int h = h0 + (p >> 3), w = w0 + (p & 7);
    size_t tok = (size_t)(b * 4096 + h * 64 + w) * 256;
    const float* row = xa + tok;
    float v0 = row[l], v1 = row[l + 64], v2 = row[l + 128], v3 = row[l + 192];
    float s = v0 + v1 + v2 + v3;
#pragma unroll
    for (int off = 32; off; off >>= 1) s += __shfl_xor(s, off);
    float mu = s * (1.f / 256.f);
    float d0 = v0 - mu, d1 = v1 - mu, d2 = v2 - mu, d3 = v3 - mu;
    float sq = d0 * d0 + d1 * d1 + d2 * d2 + d3 * d3;
#pragma unroll
    for (int off = 32; off; off >>= 1) sq += __shfl_xor(sq, off);
    float rstd = rsqrtf(sq * (1.f / 256.f) + 1e-6f);
    float n0 = d0 * rstd, n1 = d1 * rstd, n2 = d2 * rstd, n3 = d3 * rstd;
    __bf16* o = lnb + tok;
    o[l]       = (__bf16)(n0 * ga + ba);
    o[l + 64]  = (__bf16)(n1 * gb2 + bb2);
    o[l + 128] = (__bf16)(n2 * gc + bc);
    o[l + 192] = (__bf16)(n3 * gd + bd);
    a0 += n0; a1 += n1; a2 += n2; a3 += n3;
  }
  part[wave][l] = a0; part[wave][l + 64] = a1;
  part[wave][l + 128] = a2; part[wave][l + 192] = a3;
  __syncthreads();
  if (wave == 0) {
    for (int ch = l; ch < 256; ch += 64) {
      float s2 = part[0][ch] + part[1][ch] + part[2][ch] + part[3][ch];
      lnm[(size_t)(b * 64 + r) * 256 + ch] = g[ch] * (s2 * (1.f / 64.f)) + bb[ch];
    }
  }
}

// ---------------------------------------------------------------------------
// Weight prep: bf16-convert qkv_w [768][256], out_w [256][256],
// transpose+convert mlp_w1 [256][768]->[768][256], mlp_w2 [768][256]->[256][768],
// plus fp32 transpose of qkv_w's first 512 rows: wqkt[k2][c] (for qkr).
// ---------------------------------------------------------------------------
__global__ __launch_bounds__(256) void wprep_kernel(
    const float* __restrict__ qkv_w, const float* __restrict__ out_w,
    const float* __restrict__ w1, const float* __restrict__ w2,
    __bf16* __restrict__ wq, __bf16* __restrict__ wo,
    __bf16* __restrict__ w1t, __bf16* __restrict__ w2t,
    float* __restrict__ wqkt) {
  int i = blockIdx.x * 256 + threadIdx.x;
  if (i < 196608) wq[i] = (__bf16)qkv_w[i];
  if (i < 65536) wo[i] = (__bf16)out_w[i];
  if (i < 196608) {  // w1t[n][k] = w1[k][n], n<768, k<256
    int n = i >> 8, k2 = i & 255;
    w1t[i] = (__bf16)w1[k2 * 768 + n];
  }
  if (i < 196608) {  // w2t[n][k] = w2[k][n], n<256, k<768
    int n = i / 768, k2 = i % 768;
    w2t[i] = (__bf16)w2[k2 * 256 + n];
  }
  if (i < 131072) {  // wqkt[k2][c] = qkv_w[c][k2], c<512 (q,k rows), fp32 exact
    int k2 = i >> 9, c = i & 511;
    wqkt[i] = qkv_w[c * 256 + k2];
  }
}

// ---------------------------------------------------------------------------
// MFMA bf16 GEMM: C[row][col] = epi( sum_k A[row][k]*Bw[col][k] + bias[col] )
// EPI: 0 = scatter to q(bf16, pre-scaled 1/16)/k,v(bf16) seq layout;
//      2 = gelu -> bf16; 3 = res+val written NCHW fp32 (LDS-staged coalesced)
// ---------------------------------------------------------------------------
template <int EPI>
__global__ __launch_bounds__(256) void mfma_gemm(
    const __bf16* __restrict__ A, const __bf16* __restrict__ Bw,
    const float* __restrict__ bias, const float* __restrict__ res,
    float* __restrict__ out, __bf16* __restrict__ outb,
    __bf16* __restrict__ qd, __bf16* __restrict__ kd, __bf16* __restrict__ vd,
    int N, int K, int row0) {
  __shared__ __bf16 Asl[128 * 32];
  __shared__ __bf16 Bsl[128 * 32];
  int tid = threadIdx.x;
  int lane = tid & 63, wave = tid >> 6;
  int m0 = blockIdx.y * 128, n0 = blockIdx.x * 128;
  int wr = (wave >> 1) * 64, wc = (wave & 1) * 64;

  f32x4 acc[4][4];
  f32x4 z = {0.f, 0.f, 0.f, 0.f};
#pragma unroll
  for (int i = 0; i < 4; i++)
#pragma unroll
    for (int j = 0; j < 4; j++) acc[i][j] = z;

  int srow = (lane >> 2);          // 0..15
  int skoff = (lane & 3) * 8;      // 0,8,16,24
  for (int k0 = 0; k0 < K; k0 += 32) {
#pragma unroll
    for (int j = 0; j < 2; j++) {
      int rbase = wave * 32 + j * 16;
      const __bf16* ga = A + (size_t)(m0 + rbase + srow) * K + k0 + skoff;
      const __bf16* gb = Bw + (size_t)(n0 + rbase + srow) * K + k0 + skoff;
      async_copy16(ga, &Asl[rbase * 32]);
      async_copy16(gb, &Bsl[rbase * 32]);
    }
    __syncthreads();
    bf16x8 af[4], bf[4];
#pragma unroll
    for (int t = 0; t < 4; t++) {
      af[t] = *(const bf16x8*)&Asl[(wr + t * 16 + (lane & 15)) * 32 + (lane >> 4) * 8];
      bf[t] = *(const bf16x8*)&Bsl[(wc + t * 16 + (lane & 15)) * 32 + (lane >> 4) * 8];
    }
#pragma unroll
    for (int ti = 0; ti < 4; ti++)
#pragma unroll
      for (int tj = 0; tj < 4; tj++)
        acc[ti][tj] = __builtin_amdgcn_mfma_f32_16x16x32_bf16(
            af[ti], bf[tj], acc[ti][tj], 0, 0, 0);
    __syncthreads();
  }
  if (EPI == 3) {
    // LDS-staged coalesced NCHW write: out[(b*256+col)*4096+hw] in 128B runs.
    __shared__ float Ot[32][129];
    int grow0 = row0 + m0;
    int bq = grow0 >> 12, hw0 = grow0 & 4095;   // b constant per 128-row tile
    float* outp = out + (size_t)bq * 256 * 4096;
#pragma unroll
    for (int c32 = 0; c32 < 4; c32++) {
      if ((wave >> 1) == (c32 >> 1)) {
        int tibase = (c32 & 1) * 2;
#pragma unroll
        for (int tt = 0; tt < 2; tt++) {
          int ti = tibase + tt;
#pragma unroll
          for (int tj = 0; tj < 4; tj++) {
            int coll = wc + tj * 16 + (lane & 15);
            float bv = bias[n0 + coll];
#pragma unroll
            for (int reg = 0; reg < 4; reg++) {
              int rowl = wr + ti * 16 + (lane >> 4) * 4 + reg;
              int grow = grow0 + rowl;
              Ot[rowl - c32 * 32][coll] =
                  acc[ti][tj][reg] + bv + res[(size_t)grow * 256 + n0 + coll];
            }
          }
        }
      }
      __syncthreads();
      {
        // all 4 waves cover 128 cols: wave owns cols [wave*32, wave*32+32)
        int rl = lane & 31, ch = lane >> 5;
#pragma unroll
        for (int cc = 0; cc < 16; cc++) {
          int col = wave * 32 + cc * 2 + ch;
          outp[(size_t)(n0 + col) * 4096 + hw0 + c32 * 32 + rl] = Ot[rl][col];
        }
      }
      __syncthreads();
    }
  } else {
    // generic epilogue: C/D layout col=lane&15, row=(lane>>4)*4+reg
#pragma unroll
    for (int ti = 0; ti < 4; ti++) {
#pragma unroll
      for (int tj = 0; tj < 4; tj++) {
        int colg = n0 + wc + tj * 16 + (lane & 15);
        float bv = bias[colg];
#pragma unroll
        for (int reg = 0; reg < 4; reg++) {
          int rowg = m0 + wr + ti * 16 + (lane >> 4) * 4 + reg;
          float val = acc[ti][tj][reg] + bv;
          if (EPI == 0) {
            int tns = colg >> 8, cc = colg & 255, m = cc >> 5, d = cc & 31;
            int grow = row0 + rowg;
            int b = grow >> 12, hw = grow & 4095, h = hw >> 6, w = hw & 63;
            int r = ((h >> 3) << 3) | (w >> 3), s2 = ((h & 7) << 3) | (w & 7);
            size_t addr = (size_t)(b * 8 + m) * 131072 + r * 2048 + s2 * 32 + d;
            if (tns == 0) qd[addr] = (__bf16)(val * 0.0625f);  // fold C^-0.5
            else if (tns == 1) kd[addr] = (__bf16)val;
            else vd[addr] = (__bf16)val;
          } else if (EPI == 2) {
            outb[(size_t)rowg * N + colg] =
                (__bf16)(0.5f * val * (1.f + erff(val * 0.70710678118654752f)));
          }
        }
      }
    }
  }
}

// ---------------------------------------------------------------------------
// FUSED out-projection + residual + LN2: 512 thr, 128x256 tile (full C rows),
// grid = 256 row-blocks. Replaces mfma_gemm<1> + ln_kernel.
// ---------------------------------------------------------------------------
__global__ __launch_bounds__(512) void gemm_ln_kernel(
    const __bf16* A, const __bf16* __restrict__ Bw,
    const float* __restrict__ bias, float* __restrict__ xa,
    const float* __restrict__ g2, const float* __restrict__ b2,
    __bf16* lnbo) {
  __shared__ __bf16 Asl[128 * 32];
  __shared__ __bf16 Bsl[256 * 32];
  __shared__ float part1[128][4];
  __shared__ float part2[128][4];
  __shared__ float muv[128];
  __shared__ float rsv[128];
  int tid = threadIdx.x;
  int lane = tid & 63, wave = tid >> 6;
  int m0 = blockIdx.x * 128;
  int wr = (wave >> 2) * 64, wc = (wave & 3) * 64;

  f32x4 acc[4][4];
  f32x4 z = {0.f, 0.f, 0.f, 0.f};
#pragma unroll
  for (int i = 0; i < 4; i++)
#pragma unroll
    for (int j = 0; j < 4; j++) acc[i][j] = z;

  int srow = lane >> 2, skoff = (lane & 3) * 8;
  for (int k0 = 0; k0 < 256; k0 += 32) {
#pragma unroll
    for (int j = 0; j < 3; j++) {
      int seg = wave + 8 * j;
      if (seg < 8) {
        const __bf16* ga = A + (size_t)(m0 + seg * 16 + srow) * 256 + k0 + skoff;
        async_copy16(ga, &Asl[seg * 16 * 32]);
      } else {
        const __bf16* gb =
            Bw + (size_t)((seg - 8) * 16 + srow) * 256 + k0 + skoff;
        async_copy16(gb, &Bsl[(seg - 8) * 16 * 32]);
      }
    }
    __syncthreads();
    bf16x8 af[4], bf[4];
#pragma unroll
    for (int t = 0; t < 4; t++) {
      af[t] = *(const bf16x8*)&Asl[(wr + t * 16 + (lane & 15)) * 32 + (lane >> 4) * 8];
      bf[t] = *(const bf16x8*)&Bsl[(wc + t * 16 + (lane & 15)) * 32 + (lane >> 4) * 8];
    }
#pragma unroll
    for (int ti = 0; ti < 4; ti++)
#pragma unroll
      for (int tj = 0; tj < 4; tj++)
        acc[ti][tj] = __builtin_amdgcn_mfma_f32_16x16x32_bf16(
            af[ti], bf[tj], acc[ti][tj], 0, 0, 0);
    __syncthreads();
  }

  // epilogue phase 1: v = acc + bias + res; write xa; accumulate partials
  float s1[16], s2v[16];
#pragma unroll
  for (int k = 0; k < 16; k++) { s1[k] = 0.f; s2v[k] = 0.f; }
#pragma unroll
  for (int tj = 0; tj < 4; tj++) {
    int colg = wc + tj * 16 + (lane & 15);
    float bv = bias[colg];
#pragma unroll
    for (int ti = 0; ti < 4; ti++) {
#pragma unroll
      for (int reg = 0; reg < 4; reg++) {
        int rowg = m0 + wr + ti * 16 + (lane >> 4) * 4 + reg;
        float v = acc[ti][tj][reg] + bv + xa[(size_t)rowg * 256 + colg];
        xa[(size_t)rowg * 256 + colg] = v;
        acc[ti][tj][reg] = v;  // keep for phase 2
        s1[ti * 4 + reg] += v;
        s2v[ti * 4 + reg] += v * v;
      }
    }
  }
  // reduce over the 16-lane col group (lane&15)
#pragma unroll
  for (int off = 1; off < 16; off <<= 1) {
#pragma unroll
    for (int k = 0; k < 16; k++) {
      s1[k] += __shfl_xor(s1[k], off);
      s2v[k] += __shfl_xor(s2v[k], off);
    }
  }
  if ((lane & 15) == 0) {
    int q = lane >> 4;
#pragma unroll
    for (int k = 0; k < 16; k++) {
      int rowl = wr + (k >> 2) * 16 + q * 4 + (k & 3);
      part1[rowl][wave & 3] = s1[k];
      part2[rowl][wave & 3] = s2v[k];
    }
  }
  __syncthreads();
  if (tid < 128) {
    float S1 = part1[tid][0] + part1[tid][1] + part1[tid][2] + part1[tid][3];
    float S2 = part2[tid][0] + part2[tid][1] + part2[tid][2] + part2[tid][3];
    float mu = S1 * (1.f / 256.f);
    float var = S2 * (1.f / 256.f) - mu * mu;
    muv[tid] = mu;
    rsv[tid] = rsqrtf(var + 1e-6f);
  }
  __syncthreads();
  // phase 2: lnb = (v - mu)*rstd*g + b
#pragma unroll
  for (int tj = 0; tj < 4; tj++) {
    int colg = wc + tj * 16 + (lane & 15);
    float gg = g2[colg], bb = b2[colg];
#pragma unroll
    for (int ti = 0; ti < 4; ti++) {
#pragma unroll
      for (int reg = 0; reg < 4; reg++) {
        int rowl = wr + ti * 16 + (lane >> 4) * 4 + reg;
        int rowg = m0 + rowl;
        lnbo[(size_t)rowg * 256 + colg] =
            (__bf16)((acc[ti][tj][reg] - muv[rowl]) * rsv[rowl] * gg + bb);
      }
    }
  }
}

// ---------------------------------------------------------------------------
// qkr v2: 128 blocks x 4 regions. Weights read COALESCED from wqkt [k2][c]
// (fp32 transpose). Per-output sum is the identical ascending-k2 single-
// accumulator order as v1 -> bit-identical routing inputs.
// ---------------------------------------------------------------------------
__global__ __launch_bounds__(256) void qkr_kernel(
    const float* __restrict__ lnm, const float* __restrict__ wqkt,
    const float* __restrict__ qkv_b, float* __restrict__ qr,
    float* __restrict__ kr) {
  __shared__ float xm[4][256];
  int blk = blockIdx.x;   // 128: rows blk*4 .. blk*4+3 of [512][256]
  int tid = threadIdx.x;
#pragma unroll
  for (int j = 0; j < 4; j++)
    xm[j][tid] = lnm[(size_t)(blk * 4 + j) * 256 + tid];
  __syncthreads();
  int c = tid;
  float aq0 = 0.f, aq1 = 0.f, aq2 = 0.f, aq3 = 0.f;
  float ak0 = 0.f, ak1 = 0.f, ak2 = 0.f, ak3 = 0.f;
  for (int k2 = 0; k2 < 256; k2++) {
    float wqv = wqkt[k2 * 512 + c];
    float wkv = wqkt[k2 * 512 + 256 + c];
    float x0 = xm[0][k2], x1 = xm[1][k2], x2 = xm[2][k2], x3 = xm[3][k2];
    aq0 += wqv * x0; ak0 += wkv * x0;
    aq1 += wqv * x1; ak1 += wkv * x1;
    aq2 += wqv * x2; ak2 += wkv * x2;
    aq3 += wqv * x3; ak3 += wkv * x3;
  }
  float bq = qkv_b[c], bk = qkv_b[256 + c];
  size_t base = (size_t)(blk * 4) * 256 + c;
  qr[base]       = aq0 + bq; kr[base]       = ak0 + bk;
  qr[base + 256] = aq1 + bq; kr[base + 256] = ak1 + bk;
  qr[base + 512] = aq2 + bq; kr[base + 512] = ak2 + bk;
  qr[base + 768] = aq3 + bq; kr[base + 768] = ak3 + bk;
}

// ---------------------------------------------------------------------------
// Routing v2: grid (16 row-groups, 8 batches), 4 waves/block.
// ---------------------------------------------------------------------------
__global__ __launch_bounds__(256) void routing_kernel(
    const float* __restrict__ qr, const float* __restrict__ kr,
    int* __restrict__ idxout) {
  __shared__ float Ar[4][64];
  int b = blockIdx.y, rg = blockIdx.x;
  int tid = threadIdx.x;
  int lane = tid & 63, wave = tid >> 6;
  int i = (rg << 2) + wave;
  const float* qrow = qr + (size_t)(b * 64 + i) * 256;
  const float* krow = kr + (size_t)(b * 64 + lane) * 256;
  float acc = 0.f;
  for (int c = 0; c < 256; c++) acc += qrow[c] * krow[c];
  Ar[wave][lane] = acc;
  __syncthreads();
  if (lane == 0) {
    float v0 = -INFINITY, v1 = -INFINITY, v2 = -INFINITY, v3 = -INFINITY;
    int i0 = 0, i1 = 0, i2 = 0, i3 = 0;
    for (int j = 0; j < 64; j++) {
      float s = Ar[wave][j];
      if (s > v0)      { v3=v2;i3=i2; v2=v1;i2=i1; v1=v0;i1=i0; v0=s;i0=j; }
      else if (s > v1) { v3=v2;i3=i2; v2=v1;i2=i1; v1=s;i1=j; }
      else if (s > v2) { v3=v2;i3=i2; v2=s;i2=j; }
      else if (s > v3) { v3=s;i3=j; }
    }
    int* op = idxout + (b * 64 + i) * 4;
    op[0] = i0; op[1] = i1; op[2] = i2; op[3] = i3;
  }
}

// ---------------------------------------------------------------------------
// Attention per (b,m,r) — MFMA, 512 threads / 8 waves, chunks concurrent.
// wsum via append-ones MFMA during PV; fixed fully-unrolled 16-bit radix.
// LDS: Vt 16K (rotation) + Sb[64][256] 32K = 48.1KB -> 3 blocks/CU, 24 w/CU.
// ---------------------------------------------------------------------------
__global__ __launch_bounds__(512, 6) void attn_kernel(
    const __bf16* __restrict__ qbf, float* __restrict__ aout,
    const __bf16* __restrict__ kbuf, const __bf16* __restrict__ vbuf,
    const int* __restrict__ idx) {
  __shared__ __bf16 Vt[32 * 256];   // rotation layout
  __shared__ __bf16 Sb[64 * 256];   // [row][key ^ ((row&7)<<3)] : S then P
  int blk = blockIdx.x; int r = blk & 63; int m = (blk >> 6) & 7; int b = blk >> 9;
  int tid = threadIdx.x;
  int lane = tid & 63, wave = tid >> 6;   // wave 0..7
  const int* ip = idx + (b * 64 + r) * 4;
  size_t bm = (size_t)(b * 8 + m) * 131072;
  int rgs[4] = {ip[0], ip[1], ip[2], ip[3]};

  // ---- stage V -> Vt (rotation layout), conflict-free b16 writes ----
  {
    int tid2 = tid & 255;
    int rid = tid >> 8;               // 0..1
    int s = tid2 >> 2, g8 = tid2 & 3; // key-in-region, d-chunk
#pragma unroll
    for (int t = 0; t < 2; t++) {
      int rgi = (t << 1) | rid;
      int rlo = (rgi & 1) ? rgs[1] : rgs[0];
      int rhi = (rgi & 1) ? rgs[3] : rgs[2];
      int rgv = (rgi & 2) ? rhi : rlo;
      const uint4* sv = (const uint4*)(vbuf + bm + (size_t)rgv * 2048);
      uint4 vw = sv[tid2];
      int kk = (rgi << 6) | s;
      int ck = kk >> 3, klo = kk & 7;
      union { uint4 u; __bf16 h[8]; } vu; vu.u = vw;
#pragma unroll
      for (int j = 0; j < 8; j++) {
        int d = (g8 << 3) + j;
        int cp = (ck + j + (g8 << 1)) & 31;   // (ck + (d&7) + 2*(d>>3)) & 31
        Vt[(d << 8) + (cp << 3) + klo] = vu.h[j];
      }
    }
  }

  // ---- Q fragments for this wave's chunk (c = wave>>2) ----
  int chnk = wave >> 2;
  const __bf16* qb = qbf + bm + r * 2048;
  bf16x8 qf[2];
#pragma unroll
  for (int rtl = 0; rtl < 2; rtl++) {
    int rt = (chnk << 1) + rtl;
    qf[rtl] = *(const bf16x8*)(qb + ((rt * 16 + (lane & 15)) << 5) + ((lane >> 4) << 3));
  }

  // ---- K fragments direct from global: region rgs[wave&3] ----
  bf16x8 kf[4];
  {
    int rw0 = (wave & 1) ? rgs[1] : rgs[0];
    int rw1 = (wave & 1) ? rgs[3] : rgs[2];
    int rgw = (wave & 2) ? rw1 : rw0;
    const __bf16* kb = kbuf + bm + (size_t)rgw * 2048;
#pragma unroll
    for (int kt4 = 0; kt4 < 4; kt4++)
      kf[kt4] = *(const bf16x8*)(kb + ((kt4 * 16 + (lane & 15)) << 5) + ((lane >> 4) << 3));
  }

  // ---- S^T = K @ Q^T: wave covers (chunk, region) pair ----
#pragma unroll
  for (int kt4 = 0; kt4 < 4; kt4++) {
    int kt = ((wave & 3) << 2) + kt4;   // global key-tile
#pragma unroll
    for (int rtl = 0; rtl < 2; rtl++) {
      f32x4 st = {0.f, 0.f, 0.f, 0.f};
      st = __builtin_amdgcn_mfma_f32_16x16x32_bf16(kf[kt4], qf[rtl], st, 0, 0, 0);
      // D: M(key)=kt*16+4*(lane>>4)+reg ; N(row)=chunk*32+rtl*16+(lane&15)
      int row = (chnk << 5) + (rtl << 4) + (lane & 15);   // 0..63
      int key0 = (kt << 4) + ((lane >> 4) << 2);
      bf16x4 sv4;
#pragma unroll
      for (int j = 0; j < 4; j++) sv4[j] = (__bf16)st[j];
      *(bf16x4*)&Sb[row * 256 + (key0 ^ ((row & 7) << 3))] = sv4;
    }
  }
  __syncthreads();

  // ---- select top-32 per row: rows 8*wave .. 8*wave+7 (fixed 16 bits) ----
  {
    int row0 = wave << 3;
    unsigned uk[8][4];
#pragma unroll
    for (int i = 0; i < 8; i++) {
      us4 q4 = *(const us4*)&Sb[(row0 + i) * 256 + ((lane << 2) ^ (i << 3))];
#pragma unroll
      for (int t = 0; t < 4; t++) {
        unsigned bits = q4[t];
        uk[i][t] = (bits ^ ((0u - (bits >> 15)) | 0x8000u)) & 0xFFFFu;
      }
    }
    unsigned p[8];
#pragma unroll
    for (int i = 0; i < 8; i++) p[i] = 0;
#pragma unroll
    for (int bit = 15; bit >= 0; --bit) {
      unsigned msk = 1u << bit;
#pragma unroll
      for (int i = 0; i < 8; i++) {
        unsigned cc = p[i] | msk;
        int n = __popcll(__ballot(uk[i][0] >= cc)) + __popcll(__ballot(uk[i][1] >= cc)) +
                __popcll(__ballot(uk[i][2] >= cc)) + __popcll(__ballot(uk[i][3] >= cc));
        if (n >= 32) p[i] = cc;
      }
    }
#pragma unroll
    for (int i = 0; i < 8; i++) {
      unsigned T = p[i];
      unsigned ub = T << 16;
      unsigned tb = (ub & 0x80000000u) ? (ub ^ 0x80000000u) : ~ub;
      float Tv = __uint_as_float(tb);
      unsigned long long gbb[4], ebb[4];
#pragma unroll
      for (int t = 0; t < 4; t++) {
        gbb[t] = __ballot(uk[i][t] > T);
        ebb[t] = __ballot(uk[i][t] == T);
      }
      int cgt = __popcll(gbb[0]) + __popcll(gbb[1]) + __popcll(gbb[2]) + __popcll(gbb[3]);
      int be1 = __popcll(ebb[0]), be2 = be1 + __popcll(ebb[1]), be3 = be2 + __popcll(ebb[2]);
      int bes[4] = {0, be1, be2, be3};
      int need = 32 - cgt;
      bf16x4 pq;
#pragma unroll
      for (int t = 0; t < 4; t++) {
        int ret = bes[t] + __builtin_amdgcn_mbcnt_hi(
                               (unsigned)(ebb[t] >> 32),
                               __builtin_amdgcn_mbcnt_lo((unsigned)ebb[t], 0));
        bool isg = uk[i][t] > T;
        bool sel = isg || (uk[i][t] == T && ret < need);
        unsigned bits = uk[i][t] ^ ((uk[i][t] >> 15) ? 0x8000u : 0xFFFFu);
        float scv = __uint_as_float(bits << 16);
        float w = sel ? __expf(scv - Tv) : 0.f;
        pq[t] = (__bf16)w;
      }
      *(bf16x4*)&Sb[(row0 + i) * 256 + ((lane << 2) ^ (i << 3))] = pq;
    }
  }
  __syncthreads();

  // ---- O = P @ V via MFMA; wsum via append-ones MFMA (no shfl chains) ----
  f32x4 oacc = {0.f, 0.f, 0.f, 0.f};
  f32x4 wacc = {0.f, 0.f, 0.f, 0.f};
  bf16x8 ones;
#pragma unroll
  for (int j = 0; j < 8; j++) ones[j] = (__bf16)1.0f;
  int prow = ((wave >> 1) << 4) + (lane & 15);   // row 0..63
  int drow = ((wave & 1) << 4) + (lane & 15);    // d 0..31
  int koff = (lane >> 4) << 3;
#pragma unroll
  for (int ks = 0; ks < 8; ks++) {
    bf16x8 pa = *(const bf16x8*)&Sb[prow * 256 + (((ks << 5) + koff) ^ ((prow & 7) << 3))];
    int ck = (ks << 2) + (lane >> 4);
    int cp = (ck + (drow & 7) + ((drow >> 3) << 1)) & 31;
    bf16x8 vb = *(const bf16x8*)&Vt[(drow << 8) + (cp << 3)];
    oacc = __builtin_amdgcn_mfma_f32_16x16x32_bf16(pa, vb, oacc, 0, 0, 0);
    wacc = __builtin_amdgcn_mfma_f32_16x16x32_bf16(pa, ones, wacc, 0, 0, 0);
  }
  {
    int rl = ((wave >> 1) << 4) + ((lane >> 4) << 2);
    float* ob = aout + bm + r * 2048;
#pragma unroll
    for (int reg = 0; reg < 4; reg++) {
      float rinv = __builtin_amdgcn_rcpf(wacc[reg]);
      int rowg = rl + reg;
      ob[(rowg << 5) + ((wave & 1) << 4) + (lane & 15)] = oacc[reg] * rinv;
    }
  }
}

// ---------------------------------------------------------------------------
// K6: t = seq2grid(attn_out) + dwconv5x5(v) + lepe_b, NHWC bf16 out.
// ---------------------------------------------------------------------------
__global__ __launch_bounds__(256) void lepe_kernel(
    const float* __restrict__ ao, const __bf16* __restrict__ v,
    const float* __restrict__ lw, const float* __restrict__ lb,
    __bf16* __restrict__ tout) {
  __shared__ float Ls[144][32];
  __shared__ float Ws[25][32];
  int blk = blockIdx.x;  // 8*8*64
  int b = blk >> 9, m = (blk >> 6) & 7, r = blk & 63;
  int h0 = (r >> 3) << 3, w0 = (r & 7) << 3;
  int tid = threadIdx.x, d = tid & 31;
  size_t bm = (size_t)(b * 8 + m) * 131072;
  for (int i = tid; i < 144 * 32; i += 256) {
    int pos = i >> 5, dd = i & 31;
    int hh = h0 + (pos / 12) - 2, ww = w0 + (pos % 12) - 2;
    float val = 0.f;
    if (hh >= 0 && hh < 64 && ww >= 0 && ww < 64) {
      int r2 = ((hh >> 3) << 3) | (ww >> 3), s2 = ((hh & 7) << 3) | (ww & 7);
      val = (float)v[bm + r2 * 2048 + s2 * 32 + dd];
    }
    Ls[pos][dd] = val;
  }
  for (int i = tid; i < 800; i += 256) {
    int tap = i >> 5, dd = i & 31;
    Ws[tap][dd] = lw[(m * 32 + dd) * 25 + tap];
  }
  __syncthreads();
  int c = m * 32 + d;
  float bias = lb[c];
  for (int j = 0; j < 8; j++) {
    int p = (tid >> 5) + (j << 3);
    int ph = p >> 3, pww = p & 7;
    float acc = bias;
#pragma unroll
    for (int dh = 0; dh < 5; dh++)
#pragma unroll
      for (int dw = 0; dw < 5; dw++)
        acc += Ls[(ph + dh) * 12 + (pww + dw)][d] * Ws[dh * 5 + dw][d];
    acc += ao[bm + r * 2048 + p * 32 + d];
    tout[((size_t)(b * 4096 + (h0 + ph) * 64 + (w0 + pww))) * 256 + c] =
        (__bf16)acc;
  }
}

extern "C" void kernel_launch(void* const* d_in, const int* in_sizes, int n_in,
                              void* d_out, int out_size, void* d_ws, size_t ws_size,
                              hipStream_t stream) {
  (void)in_sizes; (void)n_in; (void)out_size; (void)ws_size;
  const float* x      = (const float*)d_in[0];
  const float* pos_w  = (const float*)d_in[1];
  const float* pos_b  = (const float*)d_in[2];
  const float* ln1_g  = (const float*)d_in[3];
  const float* ln1_b  = (const float*)d_in[4];
  const float* qkv_w  = (const float*)d_in[5];
  const float* qkv_b  = (const float*)d_in[6];
  const float* lepe_w = (const float*)d_in[7];
  const float* lepe_b = (const float*)d_in[8];
  const float* out_w  = (const float*)d_in[9];
  const float* out_b  = (const float*)d_in[10];
  const float* ln2_g  = (const float*)d_in[11];
  const float* ln2_b  = (const float*)d_in[12];
  const float* mlp_w1 = (const float*)d_in[13];
  const float* mlp_b1 = (const float*)d_in[14];
  const float* mlp_w2 = (const float*)d_in[15];
  const float* mlp_b2 = (const float*)d_in[16];

  float* ws = (float*)d_ws;
  const size_t P = 8ull * 4096 * 256;  // 8.39M floats
  size_t off = 0;
  float* xa = ws + off; off += P;        // residual stream NHWC fp32
  float* q  = ws + off; off += P;        // xt scratch; later attn OUT (fp32)
  __bf16* k = (__bf16*)(ws + off); off += P / 2;   // k bf16 seq
  __bf16* v = (__bf16*)(ws + off); off += P / 2;   // v bf16 seq
  __bf16* lnb = (__bf16*)(ws + off); off += P / 2; // bf16 activations
  __bf16* hb  = (__bf16*)(ws + off); off += 12582912; // MLP hidden [32768][768] bf16
  __bf16* wq  = (__bf16*)(ws + off); off += 98304;   // [768][256]
  __bf16* wo  = (__bf16*)(ws + off); off += 32768;   // [256][256]
  __bf16* w1t = (__bf16*)(ws + off); off += 98304;   // [768][256]
  __bf16* w2t = (__bf16*)(ws + off); off += 98304;   // [256][768]
  float* qr  = ws + off; off += 131072;
  float* kr  = ws + off; off += 131072;
  float* lnm = ws + off; off += 131072;
  float* wqkt = ws + off; off += 131072;  // fp32 qkv_w[0:512] transposed [256][512]
  int* ridx  = (int*)(ws + off);

  // q bf16 (pre-scaled) aliases hb: hb is dead until the MLP (step 10),
  // qbf is dead after attn (step 6) — no temporal overlap.
  __bf16* qbf = hb;

  // 0) weight prep
  wprep_kernel<<<768, 256, 0, stream>>>(qkv_w, out_w, mlp_w1, mlp_w2,
                                        wq, wo, w1t, w2t, wqkt);
  // 1) NCHW -> NHWC transpose of x into q (scratch)
  transpose_kernel<<<dim3(64, 4, 8), 256, 0, stream>>>(x, q, 256, 4096);
  // 2) pos dwconv + residual
  posconv_kernel<<<2048, 256, 0, stream>>>(q, pos_w, pos_b, xa);
  // 3) FUSED LN1 + region-mean (single xa read pass)
  ln1mean_kernel<<<512, 256, 0, stream>>>(xa, ln1_g, ln1_b, lnb, lnm);
  // 4) routing path, fp32-exact (qkr v2: coalesced weights, 128 blocks)
  qkr_kernel<<<128, 256, 0, stream>>>(lnm, wqkt, qkv_b, qr, kr);
  routing_kernel<<<dim3(16, 8), 256, 0, stream>>>(qr, kr, ridx);
  // 5) qkv GEMM (MFMA bf16): q bf16 pre-scaled, k/v bf16 seq layout
  mfma_gemm<0><<<dim3(6, 256), 256, 0, stream>>>(
      lnb, wq, qkv_b, nullptr, nullptr, nullptr, qbf, k, v, 768, 256, 0);
  // 6) sparse attention (MFMA, 512 thr; writes fp32 into q)
  attn_kernel<<<4096, 512, 0, stream>>>(qbf, q, k, v, ridx);
  // 7) seq2grid + LEPE dwconv5x5 -> lnb (bf16 t)
  lepe_kernel<<<4096, 256, 0, stream>>>(q, v, lepe_w, lepe_b, lnb);
  // 8+9) FUSED out projection + residual + LN2 (writes xa fp32 and lnb bf16)
  gemm_ln_kernel<<<256, 512, 0, stream>>>(lnb, wo, out_b, xa, ln2_g, ln2_b,
                                          lnb);
  // 10) MLP single pass; mlp2 writes d_out NCHW directly (LDS-coalesced)
  mfma_gemm<2><<<dim3(6, 256), 256, 0, stream>>>(
      lnb, w1t, mlp_b1, nullptr, nullptr, hb, nullptr, nullptr, nullptr,
      768, 256, 0);
  mfma_gemm<3><<<dim3(2, 256), 256, 0, stream>>>(
      hb, w2t, mlp_b2, xa, (float*)d_out, nullptr, nullptr, nullptr, nullptr,
      256, 768, 0);
}